// Round 15
// baseline (1210.678 us; speedup 1.0000x reference)
//
#include <hip/hip_runtime.h>
#include <hip/hip_bf16.h>
#include <math.h>

// Problem dims
#define BB 32
#define TE 80
#define FEAT 4096
#define HH 256
#define W2V 256
#define TD 30
#define VV 32000
#define G4 1024   // 4*H

typedef unsigned short u16;
typedef unsigned int u32;
using f32x4 = __attribute__((ext_vector_type(4))) float;
using bf16x8 = __attribute__((ext_vector_type(8))) short;
using f16x2 = __attribute__((ext_vector_type(2))) _Float16;

#define SENT 0xFFFFFFFFu
#define GUARD (1 << 22)

__device__ __forceinline__ float sigm(float x) { return 1.0f / (1.0f + expf(-x)); }
__device__ __forceinline__ u16 f2bf(float f) {
  u32 u = __float_as_uint(f);
  u32 r = (u + 0x7FFFu + ((u >> 16) & 1u)) >> 16;
  return (u16)r;
}
__device__ __forceinline__ u32 packh2(float lo, float hi) {
  f16x2 v = {(_Float16)lo, (_Float16)hi};
  return __builtin_bit_cast(u32, v);
}
__device__ __forceinline__ u32 packbf2(float lo, float hi) {
  return (u32)f2bf(lo) | ((u32)f2bf(hi) << 16);
}

#define AT_LOAD(p)     __hip_atomic_load((p), __ATOMIC_RELAXED, __HIP_MEMORY_SCOPE_AGENT)
#define AT_STORE(p, v) __hip_atomic_store((p), (v), __ATOMIC_RELAXED, __HIP_MEMORY_SCOPE_AGENT)
#define AT_ADD(p, v)   __hip_atomic_fetch_add((p), (v), __ATOMIC_RELAXED, __HIP_MEMORY_SCOPE_AGENT)

__device__ __forceinline__ float fdot2h(f16x2 a, f16x2 b, float c) {
#if __has_builtin(__builtin_amdgcn_fdot2)
  return __builtin_amdgcn_fdot2(a, b, c, false);
#else
  return c + (float)a[0] * (float)b[0] + (float)a[1] * (float)b[1];
#endif
}

// ctrs indices
#define C_BAR 0
#define C_WRT 32
#define C_CHQ 96
#define C_RG 128   // +rg (29)

// ===========================================================================
// prep: argmax | w_ih1->bf16 | XW2 MFMA (inline cvt, +bias) | H sentinels |
// A2P sentinels | bias+misc.   3297 blocks.  (r14-proven)
// ===========================================================================
__global__ __launch_bounds__(256) void prep_kernel(
    const float* __restrict__ w_ih1, const float* __restrict__ w_ih2,
    const float* __restrict__ caption, const float* __restrict__ onehot,
    const float* __restrict__ b_ih1, const float* __restrict__ b_hh1,
    const float* __restrict__ b_ih2, const float* __restrict__ b_hh2,
    u16* __restrict__ w_ih1b, float* __restrict__ XW2,
    float* __restrict__ bias1, float* __restrict__ bias2,
    u32* __restrict__ H1H, u32* __restrict__ H2H, u32* __restrict__ A2P,
    float* __restrict__ loss, int* __restrict__ ctrs,
    int* __restrict__ targets) {
  __shared__ __align__(16) char psm[50688];
  int blk = blockIdx.x, tid = threadIdx.x;
  if (blk < 928) {
    int k = blk;  // (s-1)*32 + b
    int s = (k >> 5) + 1, b = k & 31;
    const float* row = &onehot[((size_t)b * TD + s) * VV];
    float bv = -INFINITY;
    int bi = 0x7fffffff;
    for (int v = tid; v < VV; v += 256) {
      float x = row[v];
      if (x > bv || (x == bv && v < bi)) { bv = x; bi = v; }
    }
    float* sv = (float*)psm;
    int* si = (int*)(psm + 1024);
    sv[tid] = bv; si[tid] = bi;
    __syncthreads();
    for (int off = 128; off; off >>= 1) {
      if (tid < off) {
        float ov = sv[tid + off]; int oi = si[tid + off];
        if (ov > sv[tid] || (ov == sv[tid] && oi < si[tid])) { sv[tid] = ov; si[tid] = oi; }
      }
      __syncthreads();
    }
    if (tid == 0) targets[k] = si[0];
  } else if (blk < 1952) {
    int i0 = (blk - 928) * 1024 + tid;
#pragma unroll
    for (int ii = 0; ii < 4; ++ii) {
      int i = i0 + ii * 256;
      float4 v = *(const float4*)&w_ih1[(size_t)i * 4];
      *(ushort4*)&w_ih1b[(size_t)i * 4] =
          make_ushort4(f2bf(v.x), f2bf(v.y), f2bf(v.z), f2bf(v.w));
    }
  } else if (blk < 2416) {
    int k = blk - 1952, nb = k & 15, t = k >> 4;
    u16* As = (u16*)psm;                 // [32][264]
    u16* Bs = (u16*)(psm + 16896);       // [64][264]
    int nBase = nb * 64;
#pragma unroll
    for (int it = 0; it < 4; ++it) {
      int i = it * 256 + tid;
      int r = i >> 5, c8 = i & 31;
      const float* src = &caption[((size_t)r * TD + t) * 256 + c8 * 8];
      float4 v0 = *(const float4*)src;
      float4 v1 = *(const float4*)(src + 4);
      u16* dst = &As[r * 264 + c8 * 8];
      *(ushort4*)dst = make_ushort4(f2bf(v0.x), f2bf(v0.y), f2bf(v0.z), f2bf(v0.w));
      *(ushort4*)(dst + 4) = make_ushort4(f2bf(v1.x), f2bf(v1.y), f2bf(v1.z), f2bf(v1.w));
    }
#pragma unroll
    for (int it = 0; it < 8; ++it) {
      int i = it * 256 + tid;
      int r = i >> 5, c8 = i & 31;
      const float* src = &w_ih2[(size_t)(nBase + r) * 512 + c8 * 8];
      float4 v0 = *(const float4*)src;
      float4 v1 = *(const float4*)(src + 4);
      u16* dst = &Bs[r * 264 + c8 * 8];
      *(ushort4*)dst = make_ushort4(f2bf(v0.x), f2bf(v0.y), f2bf(v0.z), f2bf(v0.w));
      *(ushort4*)(dst + 4) = make_ushort4(f2bf(v1.x), f2bf(v1.y), f2bf(v1.z), f2bf(v1.w));
    }
    __syncthreads();
    int lane = tid & 63, w = tid >> 6;
    int lrow = lane & 15, lk = (lane >> 4) * 8;
    f32x4 acc[2];
    acc[0] = (f32x4){0.f, 0.f, 0.f, 0.f};
    acc[1] = (f32x4){0.f, 0.f, 0.f, 0.f};
#pragma unroll
    for (int ks = 0; ks < 8; ++ks) {
      bf16x8 bfr = *(const bf16x8*)&Bs[(w * 16 + lrow) * 264 + ks * 32 + lk];
#pragma unroll
      for (int m = 0; m < 2; ++m) {
        bf16x8 af = *(const bf16x8*)&As[(m * 16 + lrow) * 264 + ks * 32 + lk];
        acc[m] = __builtin_amdgcn_mfma_f32_16x16x32_bf16(af, bfr, acc[m], 0, 0, 0);
      }
    }
    int col = nBase + w * 16 + (lane & 15);
    float bv = b_ih2[col] + b_hh2[col];
    int orow = (lane >> 4) * 4;
#pragma unroll
    for (int m = 0; m < 2; ++m)
#pragma unroll
      for (int qq = 0; qq < 4; ++qq) {
        int bb = m * 16 + orow + qq;
        XW2[((size_t)t * 32 + bb) * G4 + col] = acc[m][qq] + bv;
      }
  } else if (blk < 2856) {
    int i = (blk - 2416) * 256 + tid;  // uint4 idx < 112640
    uint4 z = {0u, 0u, 0u, 0u};
    uint4 s = {SENT, SENT, SENT, SENT};
    uint4 v = (i < 1024) ? z : s;      // slot T=0 = packed f16 zeros
    ((uint4*)H1H)[i] = v;
    ((uint4*)H2H)[i] = v;
  } else if (blk < 3296) {
    int i0 = (blk - 2856) * 1024 + tid;  // uint4 idx < 450560
    uint4 s = {SENT, SENT, SENT, SENT};
#pragma unroll
    for (int ii = 0; ii < 4; ++ii) ((uint4*)A2P)[i0 + ii * 256] = s;
  } else {
    for (int i = tid; i < 1024; i += 256) {
      bias1[i] = b_ih1[i] + b_hh1[i];
      bias2[i] = b_ih2[i] + b_hh2[i];
    }
    if (tid < 256) ctrs[tid] = 0;
    if (tid == 0) *loss = 0.0f;
  }
}

// ===========================================================================
// gemm_x1: X1[r][n] = feat[r][:] . w_ih1b[n][:] + bias1[n]; A f32 inline cvt.
// ===========================================================================
#define GBM 128
#define GBN 128
#define GBK 64
#define LDSTR 72

__global__ __launch_bounds__(256) void gemm_x1_kernel(
    const float* __restrict__ A, const u16* __restrict__ Bw,
    const float* __restrict__ bias, float* __restrict__ C) {
  __shared__ __align__(16) u16 As[GBM * LDSTR];
  __shared__ __align__(16) u16 Bs[GBN * LDSTR];
  int tid = threadIdx.x;
  int rBase = (blockIdx.x >> 3) * GBM;
  int nBase = (blockIdx.x & 7) * GBN;
  int lane = tid & 63, w = tid >> 6;
  int wrow = (w >> 1) * 64, wcol = (w & 1) * 64;
  int lrow = lane & 15, lk = (lane >> 4) * 8;

  f32x4 acc[4][4];
#pragma unroll
  for (int m = 0; m < 4; ++m)
#pragma unroll
    for (int n = 0; n < 4; ++n) acc[m][n] = (f32x4){0.f, 0.f, 0.f, 0.f};

  for (int k0 = 0; k0 < FEAT; k0 += GBK) {
#pragma unroll
    for (int i = 0; i < 8; ++i) {
      int f = i * 256 + tid;
      int r = f >> 4, c = (f & 15) << 2;
      float4 v = *(const float4*)&A[(size_t)(rBase + r) * FEAT + k0 + c];
      *(ushort4*)&As[r * LDSTR + c] =
          make_ushort4(f2bf(v.x), f2bf(v.y), f2bf(v.z), f2bf(v.w));
    }
#pragma unroll
    for (int i = 0; i < 4; ++i) {
      int f = i * 256 + tid;
      int r = f >> 3, c8 = f & 7;
      *(uint4*)&Bs[r * LDSTR + c8 * 8] =
          *(const uint4*)&Bw[(size_t)(nBase + r) * FEAT + k0 + c8 * 8];
    }
    __syncthreads();
#pragma unroll
    for (int s2 = 0; s2 < 2; ++s2) {
      bf16x8 af[4], bfr[4];
#pragma unroll
      for (int m = 0; m < 4; ++m)
        af[m] = *(const bf16x8*)&As[(wrow + m * 16 + lrow) * LDSTR + s2 * 32 + lk];
#pragma unroll
      for (int n = 0; n < 4; ++n)
        bfr[n] = *(const bf16x8*)&Bs[(wcol + n * 16 + lrow) * LDSTR + s2 * 32 + lk];
#pragma unroll
      for (int m = 0; m < 4; ++m)
#pragma unroll
        for (int n = 0; n < 4; ++n)
          acc[m][n] = __builtin_amdgcn_mfma_f32_16x16x32_bf16(
              af[m], bfr[n], acc[m][n], 0, 0, 0);
    }
    __syncthreads();
  }
  int orow = (lane >> 4) * 4;
  int ocol = lane & 15;
#pragma unroll
  for (int m = 0; m < 4; ++m)
#pragma unroll
    for (int n = 0; n < 4; ++n) {
      int cidx = nBase + wcol + n * 16 + ocol;
      float bv = bias[cidx];
#pragma unroll
      for (int q = 0; q < 4; ++q) {
        int r = rBase + wrow + m * 16 + orow + q;
        C[(size_t)r * G4 + cidx] = acc[m][n][q] + bv;
      }
    }
}

// ===========================================================================
// Mega cooperative kernel: chains (r14 structure) + overlapped logits/CE.
// ===========================================================================
struct RP {
  const float *X1, *XW2, *bias1, *bias2;
  const float *w_hh1, *w_ih2, *w_hh2, *w_out, *b_out;
  u32* H1H;     // [110][32][128] packed f16x2 of h1[T]
  u32* H2H;     // [110][32][128] packed f16x2 of h2[U]
  u32* A2P;     // [110][32][512] packed f16x2 pairs of a2 rows
  u32* H2NB32;  // [29][32][128] packed bf16x2 of decoder h2n
  u32 *pmaxA, *psumA, *tgtv;  // [928][2000] x2, [928]
  float* loss;
  int* ctrs;
  const int* targets;
  float* out;
};

// LDS layout (chain phase): encL 0 | hS 82240 | tmp2 82752 | gb 83776 |
// a2pS 84800 | hnew 85824 | sc 86080 | red 86400.  (logits): bS 0 |
// aS 65536 | tS 82432 | chS 82560.  (final): smM 0 | smS 2048.
#define SMEMB 86528

// Fused logits+CE partials: claim 128-col chunks; per chunk process 29 rgs
// as ready. 8 waves x 1 ntile(16 cols). Plain cacheable loads for H2NB
// (published via AT_STOREs; acquire fence after rg counter).
__device__ void do_logits(char* smem, const RP& p) {
  u16* bS = (u16*)smem;
  u16* aS = (u16*)(smem + 65536);
  int* tS = (int*)(smem + 82432);
  int* chS = (int*)(smem + 82560);
  int tid = threadIdx.x;
  int w = tid >> 6, lane = tid & 63, lcol = lane & 15, lk = lane >> 4;
  while (true) {
    if (tid == 0) *chS = AT_ADD(&p.ctrs[C_CHQ], 1);
    __syncthreads();
    int ch = *chS;
    if (ch >= 250) break;
    // stage B: cols [ch*128,+128), f32 -> bf16 MFMA layout
#pragma unroll
    for (int it = 0; it < 8; ++it) {
      int id = it * 512 + tid;  // < 4096 : nt*512 + rr*32 + kg
      int nt = id >> 9, rr = (id >> 5) & 15, kg = id & 31;
      int n = ch * 128 + nt * 16 + rr;
      const float* src = &p.w_out[(size_t)n * 256 + kg * 8];
      float4 v0 = *(const float4*)src;
      float4 v1 = *(const float4*)(src + 4);
      u16* dst = &bS[(size_t)((nt * 32 + kg) * 16 + rr) * 8];
      *(ushort4*)dst = make_ushort4(f2bf(v0.x), f2bf(v0.y), f2bf(v0.z), f2bf(v0.w));
      *(ushort4*)(dst + 4) = make_ushort4(f2bf(v1.x), f2bf(v1.y), f2bf(v1.z), f2bf(v1.w));
    }
    float bo = p.b_out[ch * 128 + w * 16 + lcol];
    for (int rg = 0; rg < 29; ++rg) {
      if (tid == 0) {
        int gd = 0;
        while (AT_LOAD(&p.ctrs[C_RG + rg]) < 128 && ++gd < GUARD)
          __builtin_amdgcn_s_sleep(1);
      }
      __syncthreads();
      __builtin_amdgcn_fence(__ATOMIC_ACQUIRE, "agent");
      // stage A: 32 rows x 256 bf16, vectorized (cacheable)
#pragma unroll
      for (int it = 0; it < 2; ++it) {
        int i = it * 512 + tid;  // < 1024 uint4
        int r = i >> 5, c8 = i & 31;
        *(uint4*)&aS[r * 264 + c8 * 8] =
            *(const uint4*)&p.H2NB32[((size_t)rg * 32 + r) * 128 + c8 * 4];
      }
      if (tid < 32) tS[tid] = p.targets[rg * 32 + tid];
      __syncthreads();
      f32x4 acc[2];
      acc[0] = (f32x4){0.f, 0.f, 0.f, 0.f};
      acc[1] = (f32x4){0.f, 0.f, 0.f, 0.f};
#pragma unroll
      for (int ks = 0; ks < 8; ++ks) {
        bf16x8 bfr = *(const bf16x8*)&bS[(size_t)((w * 32 + ks * 4 + lk) * 16 + lcol) * 8];
        bf16x8 a0 = *(const bf16x8*)&aS[lcol * 264 + ks * 32 + lk * 8];
        bf16x8 a1 = *(const bf16x8*)&aS[(16 + lcol) * 264 + ks * 32 + lk * 8];
        acc[0] = __builtin_amdgcn_mfma_f32_16x16x32_bf16(a0, bfr, acc[0], 0, 0, 0);
        acc[1] = __builtin_amdgcn_mfma_f32_16x16x32_bf16(a1, bfr, acc[1], 0, 0, 0);
      }
      int ncol = ch * 128 + w * 16 + lcol;
      int chunkW = ch * 8 + w;
#pragma unroll
      for (int m = 0; m < 2; ++m) {
        float pm[4], psv[4];
#pragma unroll
        for (int qq = 0; qq < 4; ++qq) {
          float v0 = acc[m][qq] + bo;
          int r = m * 16 + lk * 4 + qq;
          if (tS[r] == ncol) AT_STORE(&p.tgtv[rg * 32 + r], __float_as_uint(v0));
          float mx = v0;
#pragma unroll
          for (int d = 1; d < 16; d <<= 1) mx = fmaxf(mx, __shfl_xor(mx, d));
          float e = expf(v0 - mx);
#pragma unroll
          for (int d = 1; d < 16; d <<= 1) e += __shfl_xor(e, d);
          pm[qq] = mx;
          psv[qq] = e;
        }
        if (lcol == 0) {
#pragma unroll
          for (int qq = 0; qq < 4; ++qq) {
            int r2 = rg * 32 + m * 16 + lk * 4 + qq;
            AT_STORE(&p.pmaxA[(size_t)r2 * 2000 + chunkW], __float_as_uint(pm[qq]));
            AT_STORE(&p.psumA[(size_t)r2 * 2000 + chunkW], __float_as_uint(psv[qq]));
          }
        }
      }
      __syncthreads();
    }
  }
}

__global__ __launch_bounds__(512, 1) void mega_kernel(RP p) {
  __shared__ __align__(16) char smem[SMEMB];
  float* encL = (float*)smem;                    // [80][257]
  f16x2* hS = (f16x2*)(smem + 82240);            // [128]
  float* tmp2 = (float*)(smem + 82752);          // [256]
  float* gb = (float*)(smem + 83776);            // [256]
  float* a2pS = (float*)(smem + 84800);          // [256]
  float* hnew = (float*)(smem + 85824);          // [64]
  float* sc = (float*)(smem + 86080);            // [80]
  float* red = (float*)(smem + 86400);           // [4]
  int bid = blockIdx.x, tid = threadIdx.x;
  bool isL1 = bid < 128;
  int lb = isL1 ? bid : bid - 128;
  int b = lb >> 2, q = lb & 3;
  int r2 = tid >> 1, half = tid & 1;
  int g = r2 >> 6, jj = r2 & 63;
  int grow = (g << 8) + (q << 6) + jj;
  int jf = (q << 6) + tid;  // valid for tid<64

  if (isL1) {
    f16x2 wA[64], wB[64];
    {
      const float4* sA = (const float4*)(p.w_hh1 + (size_t)grow * 256 + half * 128);
      const float4* sB = (const float4*)(p.w_ih2 + (size_t)grow * 512 + 256 + half * 128);
#pragma unroll
      for (int k = 0; k < 32; ++k) {
        float4 v = sA[k];
        wA[k * 2 + 0] = f16x2{(_Float16)v.x, (_Float16)v.y};
        wA[k * 2 + 1] = f16x2{(_Float16)v.z, (_Float16)v.w};
        float4 u = sB[k];
        wB[k * 2 + 0] = f16x2{(_Float16)u.x, (_Float16)u.y};
        wB[k * 2 + 1] = f16x2{(_Float16)u.z, (_Float16)u.w};
      }
    }
    float c1 = 0.f;
    float b1v0 = 0, b1v1 = 0, b1v2 = 0, b1v3 = 0;
    if (tid < 64) {
      b1v0 = p.bias1[jf]; b1v1 = p.bias1[256 + jf];
      b1v2 = p.bias1[512 + jf]; b1v3 = p.bias1[768 + jf];
    }
    for (int T = 0; T <= 109; ++T) {
      float x0 = b1v0, x1 = b1v1, x2 = b1v2, x3 = b1v3;
      if (tid < 64 && T < TE) {
        const float* xb = &p.X1[((size_t)b * TE + T) * G4 + jf];
        x0 = xb[0]; x1 = xb[256]; x2 = xb[512]; x3 = xb[768];
      }
      if (tid < 128) {
        const u32* src = &p.H1H[((size_t)T * 32 + b) * 128 + tid];
        u32 v = AT_LOAD(src);
        int gd = 0;
        while (v == SENT && ++gd < GUARD) {
          __builtin_amdgcn_s_sleep(1);
          v = AT_LOAD(src);
        }
        hS[tid] = __builtin_bit_cast(f16x2, v);
      }
      __syncthreads();
      float a1 = 0.f, a2 = 0.f;
      {
        const uint4* hv = ((const uint4*)hS) + half * 16;
#pragma unroll
        for (int k = 0; k < 16; ++k) {
          uint4 uu = hv[k];
          f16x2 e0 = __builtin_bit_cast(f16x2, uu.x), e1 = __builtin_bit_cast(f16x2, uu.y);
          f16x2 e2 = __builtin_bit_cast(f16x2, uu.z), e3 = __builtin_bit_cast(f16x2, uu.w);
          a1 = fdot2h(e0, wA[k * 4 + 0], a1);
          a2 = fdot2h(e0, wB[k * 4 + 0], a2);
          a1 = fdot2h(e1, wA[k * 4 + 1], a1);
          a2 = fdot2h(e1, wB[k * 4 + 1], a2);
          a1 = fdot2h(e2, wA[k * 4 + 2], a1);
          a2 = fdot2h(e2, wB[k * 4 + 2], a2);
          a1 = fdot2h(e3, wA[k * 4 + 3], a1);
          a2 = fdot2h(e3, wB[k * 4 + 3], a2);
        }
      }
      a1 += __shfl_xor(a1, 1);
      a2 += __shfl_xor(a2, 1);
      float a2o = __shfl_xor(a2, 2);
      if (half == 0) gb[r2] = a1;
      if ((tid & 3) == 0 && T >= 1) {
        int pr = tid >> 2;
        int gp = pr >> 5, wp = pr & 31;
        AT_STORE(&p.A2P[((size_t)T * 32 + b) * 512 + (gp << 7) + (q << 5) + wp],
                 packh2(a2, a2o));
      }
      __syncthreads();
      if (T <= 108) {
        if (tid < 64) {
          float gi = gb[tid] + x0;
          float gf = gb[64 + tid] + x1;
          float gG = gb[128 + tid] + x2;
          float go = gb[192 + tid] + x3;
          c1 = sigm(gf) * c1 + sigm(gi) * tanhf(gG);
          hnew[tid] = sigm(go) * tanhf(c1);
        }
        if (tid < 32) {
          u32 pk = packh2(hnew[2 * tid], hnew[2 * tid + 1]);
          AT_STORE(&p.H1H[((size_t)(T + 1) * 32 + b) * 128 + (q << 5) + tid], pk);
        }
      }
    }
  } else {
    f16x2 wC[64];
    {
      const float4* sC = (const float4*)(p.w_hh2 + (size_t)grow * 256 + half * 128);
#pragma unroll
      for (int k = 0; k < 32; ++k) {
        float4 u = sC[k];
        wC[k * 2 + 0] = f16x2{(_Float16)u.x, (_Float16)u.y};
        wC[k * 2 + 1] = f16x2{(_Float16)u.z, (_Float16)u.w};
      }
    }
    float c2 = 0.f;
    float b2v0 = 0, b2v1 = 0, b2v2 = 0, b2v3 = 0;
    if (tid < 64) {
      b2v0 = p.bias2[jf]; b2v1 = p.bias2[256 + jf];
      b2v2 = p.bias2[512 + jf]; b2v3 = p.bias2[768 + jf];
    }
    for (int U = 1; U <= 109; ++U) {
      float x0 = b2v0, x1 = b2v1, x2 = b2v2, x3 = b2v3;
      if (tid < 64 && U >= 81) {
        const float* xb = &p.XW2[((size_t)(U - 81) * 32 + b) * G4 + jf];
        x0 = xb[0]; x1 = xb[256]; x2 = xb[512]; x3 = xb[768];
      }
      if (tid < 128) {
        const u32* src = &p.H2H[((size_t)(U - 1) * 32 + b) * 128 + tid];
        u32 v = AT_LOAD(src);
        int gd = 0;
        while (v == SENT && ++gd < (GUARD << 2)) v = AT_LOAD(src);
        f16x2 hp = __builtin_bit_cast(f16x2, v);
        hS[tid] = hp;
        tmp2[2 * tid] = (float)hp[0];
        tmp2[2 * tid + 1] = (float)hp[1];
      } else if (tid < 256) {
        int rr = tid - 128;
        int gp = rr >> 5, wp = rr & 31;
        const u32* src = &p.A2P[((size_t)U * 32 + b) * 512 + (gp << 7) + (q << 5) + wp];
        u32 v = AT_LOAD(src);
        int gd = 0;
        while (v == SENT && ++gd < GUARD) {
          __builtin_amdgcn_s_sleep(1);
          v = AT_LOAD(src);
        }
        f16x2 pr = __builtin_bit_cast(f16x2, v);
        a2pS[gp * 64 + 2 * wp] = (float)pr[0];
        a2pS[gp * 64 + 2 * wp + 1] = (float)pr[1];
      }
      __syncthreads();
      float a2p0 = 0, a2p1 = 0, a2p2 = 0, a2p3 = 0;
      if (tid < 64) {
        a2p0 = a2pS[tid]; a2p1 = a2pS[64 + tid];
        a2p2 = a2pS[128 + tid]; a2p3 = a2pS[192 + tid];
      }
      if (U <= 81) {
        if (U >= 2 && tid < 256) encL[(U - 2) * 257 + tid] = tmp2[tid];
      } else {
        float a = 0.f;
        if (tid < TE) {
          const float* e = &encL[tid * 257];
#pragma unroll 8
          for (int k2 = 0; k2 < 256; ++k2) a += e[k2] * tmp2[k2];
        }
        float av = (tid < TE) ? a : -INFINITY;
#pragma unroll
        for (int d = 32; d; d >>= 1) av = fmaxf(av, __shfl_xor(av, d));
        if (tid == 0) red[0] = av;
        if (tid == 64) red[1] = av;
        __syncthreads();
        float m = fmaxf(red[0], red[1]);
        float e2 = (tid < TE) ? expf(a - m) : 0.f;
        float sv = e2;
#pragma unroll
        for (int d = 32; d; d >>= 1) sv += __shfl_xor(sv, d);
        if (tid == 0) red[2] = sv;
        if (tid == 64) red[3] = sv;
        __syncthreads();
        float inv = 1.0f / (red[2] + red[3]);
        if (tid < TE) sc[tid] = e2 * inv;
        __syncthreads();
        if (tid < 256) {
          float acc = 0.f;
          for (int t2 = 0; t2 < TE; ++t2) acc += sc[t2] * encL[t2 * 257 + tid];
          tmp2[tid] = acc;
        }
        __syncthreads();
        if (tid < 128)
          hS[tid] = f16x2{(_Float16)tmp2[2 * tid], (_Float16)tmp2[2 * tid + 1]};
      }
      __syncthreads();
      float a2 = 0.f;
      {
        const uint4* hv = ((const uint4*)hS) + half * 16;
#pragma unroll
        for (int k = 0; k < 16; ++k) {
          uint4 uu = hv[k];
          a2 = fdot2h(__builtin_bit_cast(f16x2, uu.x), wC[k * 4 + 0], a2);
          a2 = fdot2h(__builtin_bit_cast(f16x2, uu.y), wC[k * 4 + 1], a2);
          a2 = fdot2h(__builtin_bit_cast(f16x2, uu.z), wC[k * 4 + 2], a2);
          a2 = fdot2h(__builtin_bit_cast(f16x2, uu.w), wC[k * 4 + 3], a2);
        }
      }
      a2 += __shfl_xor(a2, 1);
      if (half == 0) gb[r2] = a2;
      __syncthreads();
      if (tid < 64) {
        float gi = gb[tid] + a2p0 + x0;
        float gf = gb[64 + tid] + a2p1 + x1;
        float gG = gb[128 + tid] + a2p2 + x2;
        float go = gb[192 + tid] + a2p3 + x3;
        c2 = sigm(gf) * c2 + sigm(gi) * tanhf(gG);
        float h = sigm(go) * tanhf(c2);
        hnew[tid] = h;
      }
      if (tid < 32) {
        u32 pk = packh2(hnew[2 * tid], hnew[2 * tid + 1]);
        AT_STORE(&p.H2H[((size_t)U * 32 + b) * 128 + (q << 5) + tid], pk);
        if (U >= 81) {
          u32 bk = packbf2(hnew[2 * tid], hnew[2 * tid + 1]);
          AT_STORE(&p.H2NB32[((size_t)(U - 81) * 32 + b) * 128 + (q << 5) + tid], bk);
        }
      }
      if (U >= 81) {
        asm volatile("s_waitcnt vmcnt(0)" ::: "memory");
        if (tid == 0) AT_ADD(&p.ctrs[C_RG + (U - 81)], 1);
      }
    }
  }
  // ---------------- logits/CE partials (both roles) ----------------
  __syncthreads();
  do_logits(smem, p);
  // ---------------- global barrier ----------------
  asm volatile("s_waitcnt vmcnt(0)" ::: "memory");
  __syncthreads();
  if (tid == 0) {
    __hip_atomic_fetch_add(&p.ctrs[C_BAR], 1, __ATOMIC_RELEASE, __HIP_MEMORY_SCOPE_AGENT);
    int gd = 0;
    while (__hip_atomic_load(&p.ctrs[C_BAR], __ATOMIC_ACQUIRE, __HIP_MEMORY_SCOPE_AGENT) < 256 &&
           ++gd < GUARD)
      __builtin_amdgcn_s_sleep(2);
  }
  __syncthreads();
  __builtin_amdgcn_fence(__ATOMIC_ACQUIRE, "agent");
  // ---------------- final CE reduce: 4 rows per block ----------------
  {
    float* smM = (float*)smem;
    float* smS = (float*)(smem + 2048);
#pragma unroll
    for (int k = 0; k < 4; ++k) {
      int row = bid * 4 + k;
      if (row < 928) {
        const u32* pm = p.pmaxA + (size_t)row * 2000;
        const u32* psv = p.psumA + (size_t)row * 2000;
        float m = -INFINITY, s = 0.f;
        for (int c = tid; c < 2000; c += 512) {
          float pmv = __uint_as_float(pm[c]);
          float psvv = __uint_as_float(psv[c]);
          float mn = fmaxf(m, pmv);
          s = s * expf(m - mn) + psvv * expf(pmv - mn);
          m = mn;
        }
        smM[tid] = m;
        smS[tid] = s;
        __syncthreads();
        for (int off = 256; off; off >>= 1) {
          if (tid < off) {
            float m2 = smM[tid + off], s2 = smS[tid + off];
            float mn = fmaxf(smM[tid], m2);
            smS[tid] = smS[tid] * expf(smM[tid] - mn) + s2 * expf(m2 - mn);
            smM[tid] = mn;
          }
          __syncthreads();
        }
        if (tid == 0) {
          float tv = __uint_as_float(p.tgtv[row]);
          atomicAdd(p.loss, (smM[0] + logf(smS[0]) - tv) * (1.0f / 1024.0f));
        }
        __syncthreads();
      }
    }
  }
  asm volatile("s_waitcnt vmcnt(0)" ::: "memory");
  if (tid == 0) {
    int old = __hip_atomic_fetch_add(&p.ctrs[C_WRT], 1, __ATOMIC_ACQ_REL,
                                     __HIP_MEMORY_SCOPE_AGENT);
    if (old == 255) p.out[0] = __uint_as_float(AT_LOAD((u32*)p.loss));
  }
}

// ---------------------------------------------------------------------------
extern "C" void kernel_launch(void* const* d_in, const int* in_sizes, int n_in,
                              void* d_out, int out_size, void* d_ws, size_t ws_size,
                              hipStream_t stream) {
  (void)in_sizes; (void)n_in; (void)out_size; (void)ws_size;
  const float* feat    = (const float*)d_in[0];
  const float* caption = (const float*)d_in[1];
  const float* onehot  = (const float*)d_in[2];
  const float* w_ih1   = (const float*)d_in[4];
  const float* w_hh1   = (const float*)d_in[5];
  const float* b_ih1   = (const float*)d_in[6];
  const float* b_hh1   = (const float*)d_in[7];
  const float* w_ih2   = (const float*)d_in[8];
  const float* w_hh2   = (const float*)d_in[9];
  const float* b_ih2   = (const float*)d_in[10];
  const float* b_hh2   = (const float*)d_in[11];
  const float* w_out   = (const float*)d_in[12];
  const float* b_out   = (const float*)d_in[13];

  char* p = (char*)d_ws;
  auto alloc = [&](size_t bytes) {
    char* r = p;
    p += (bytes + 255) & ~(size_t)255;
    return r;
  };
  float* X1      = (float*)alloc(2560ull * 1024 * 4);    // 10.5 MB
  float* XW2     = (float*)alloc(29ull * 32 * 1024 * 4); // 3.8 MB
  float* bias1   = (float*)alloc(1024 * 4);
  float* bias2   = (float*)alloc(1024 * 4);
  u32*   H1H     = (u32*)alloc(110ull * 32 * 128 * 4);   // 1.8 MB
  u32*   H2H     = (u32*)alloc(110ull * 32 * 128 * 4);   // 1.8 MB
  u32*   A2P     = (u32*)alloc(110ull * 32 * 512 * 4);   // 7.2 MB
  u32*   H2NB32  = (u32*)alloc(29ull * 32 * 128 * 4);    // 475 KB
  u32*   pmaxA   = (u32*)alloc(928ull * 2000 * 4);       // 7.4 MB
  u32*   psumA   = (u32*)alloc(928ull * 2000 * 4);       // 7.4 MB
  u32*   tgtv    = (u32*)alloc(928 * 4);
  float* lossacc = (float*)alloc(256);
  int*   ctrs    = (int*)alloc(1024);
  int*   targets = (int*)alloc(29 * 32 * 4);
  u16*   w_ih1b  = (u16*)alloc(1024ull * 4096 * 2);      // 8.4 MB

  prep_kernel<<<3297, 256, 0, stream>>>(
      w_ih1, w_ih2, caption, onehot,
      b_ih1, b_hh1, b_ih2, b_hh2,
      w_ih1b, XW2, bias1, bias2, H1H, H2H, A2P, lossacc, ctrs, targets);

  gemm_x1_kernel<<<160, 256, 0, stream>>>(feat, w_ih1b, bias1, X1);

  RP rp;
  rp.X1 = X1; rp.XW2 = XW2; rp.bias1 = bias1; rp.bias2 = bias2;
  rp.w_hh1 = w_hh1; rp.w_ih2 = w_ih2; rp.w_hh2 = w_hh2;
  rp.w_out = w_out; rp.b_out = b_out;
  rp.H1H = H1H; rp.H2H = H2H; rp.A2P = A2P; rp.H2NB32 = H2NB32;
  rp.pmaxA = pmaxA; rp.psumA = psumA; rp.tgtv = tgtv;
  rp.loss = lossacc; rp.ctrs = ctrs; rp.targets = targets;
  rp.out = (float*)d_out;
  void* args[] = {&rp};
  hipLaunchCooperativeKernel((const void*)mega_kernel, dim3(256), dim3(512),
                             args, 0, stream);
}

// Round 16
// 896.741 us; speedup vs baseline: 1.3501x; 1.3501x over previous
//
#include <hip/hip_runtime.h>
#include <hip/hip_bf16.h>
#include <math.h>

// Problem dims
#define BB 32
#define TE 80
#define FEAT 4096
#define HH 256
#define W2V 256
#define TD 30
#define VV 32000
#define G4 1024   // 4*H

typedef unsigned short u16;
typedef unsigned int u32;
using f32x4 = __attribute__((ext_vector_type(4))) float;
using bf16x8 = __attribute__((ext_vector_type(8))) short;
using f16x2 = __attribute__((ext_vector_type(2))) _Float16;

#define SENT 0xFFFFFFFFu
#define GUARD (1 << 22)

__device__ __forceinline__ float sigm(float x) { return 1.0f / (1.0f + expf(-x)); }
__device__ __forceinline__ u16 f2bf(float f) {
  u32 u = __float_as_uint(f);
  u32 r = (u + 0x7FFFu + ((u >> 16) & 1u)) >> 16;
  return (u16)r;
}
__device__ __forceinline__ u32 packh2(float lo, float hi) {
  f16x2 v = {(_Float16)lo, (_Float16)hi};
  return __builtin_bit_cast(u32, v);
}

#define AT_LOAD(p)     __hip_atomic_load((p), __ATOMIC_RELAXED, __HIP_MEMORY_SCOPE_AGENT)
#define AT_STORE(p, v) __hip_atomic_store((p), (v), __ATOMIC_RELAXED, __HIP_MEMORY_SCOPE_AGENT)

__device__ __forceinline__ float fdot2h(f16x2 a, f16x2 b, float c) {
#if __has_builtin(__builtin_amdgcn_fdot2)
  return __builtin_amdgcn_fdot2(a, b, c, false);
#else
  return c + (float)a[0] * (float)b[0] + (float)a[1] * (float)b[1];
#endif
}

// ===========================================================================
// prepall: gemm_x1 (inline cvt A+B) | argmax | XW2 MFMA | sentinels | misc
// blocks: [0,160) | [160,1088) | [1088,1552) | [1552,2432) | 2432  => 2433
// ===========================================================================
#define GBM 128
#define GBN 128
#define GBK 64
#define LDSTR 72

__device__ void gemm_x1_body(char* smem, int blk,
                             const float* __restrict__ A, const float* __restrict__ Bw,
                             const float* __restrict__ b_ih1, const float* __restrict__ b_hh1,
                             float* __restrict__ C) {
  u16* As = (u16*)smem;
  u16* Bs = (u16*)(smem + 18432);
  int tid = threadIdx.x;
  int rBase = (blk >> 3) * GBM;
  int nBase = (blk & 7) * GBN;
  int lane = tid & 63, w = tid >> 6;
  int wrow = (w >> 1) * 64, wcol = (w & 1) * 64;
  int lrow = lane & 15, lk = (lane >> 4) * 8;

  f32x4 acc[4][4];
#pragma unroll
  for (int m = 0; m < 4; ++m)
#pragma unroll
    for (int n = 0; n < 4; ++n) acc[m][n] = (f32x4){0.f, 0.f, 0.f, 0.f};

  for (int k0 = 0; k0 < FEAT; k0 += GBK) {
#pragma unroll
    for (int i = 0; i < 8; ++i) {
      int f = i * 256 + tid;
      int r = f >> 4, c = (f & 15) << 2;
      float4 v = *(const float4*)&A[(size_t)(rBase + r) * FEAT + k0 + c];
      *(ushort4*)&As[r * LDSTR + c] =
          make_ushort4(f2bf(v.x), f2bf(v.y), f2bf(v.z), f2bf(v.w));
    }
#pragma unroll
    for (int i = 0; i < 8; ++i) {
      int f = i * 256 + tid;
      int r = f >> 4, c = (f & 15) << 2;
      float4 v = *(const float4*)&Bw[(size_t)(nBase + r) * FEAT + k0 + c];
      *(ushort4*)&Bs[r * LDSTR + c] =
          make_ushort4(f2bf(v.x), f2bf(v.y), f2bf(v.z), f2bf(v.w));
    }
    __syncthreads();
#pragma unroll
    for (int s2 = 0; s2 < 2; ++s2) {
      bf16x8 af[4], bfr[4];
#pragma unroll
      for (int m = 0; m < 4; ++m)
        af[m] = *(const bf16x8*)&As[(wrow + m * 16 + lrow) * LDSTR + s2 * 32 + lk];
#pragma unroll
      for (int n = 0; n < 4; ++n)
        bfr[n] = *(const bf16x8*)&Bs[(wcol + n * 16 + lrow) * LDSTR + s2 * 32 + lk];
#pragma unroll
      for (int m = 0; m < 4; ++m)
#pragma unroll
        for (int n = 0; n < 4; ++n)
          acc[m][n] = __builtin_amdgcn_mfma_f32_16x16x32_bf16(
              af[m], bfr[n], acc[m][n], 0, 0, 0);
    }
    __syncthreads();
  }
  int orow = (lane >> 4) * 4;
  int ocol = lane & 15;
#pragma unroll
  for (int m = 0; m < 4; ++m)
#pragma unroll
    for (int n = 0; n < 4; ++n) {
      int cidx = nBase + wcol + n * 16 + ocol;
      float bv = b_ih1[cidx] + b_hh1[cidx];
#pragma unroll
      for (int q = 0; q < 4; ++q) {
        int r = rBase + wrow + m * 16 + orow + q;
        C[(size_t)r * G4 + cidx] = acc[m][n][q] + bv;
      }
    }
}

__global__ __launch_bounds__(256) void prepall_kernel(
    const float* __restrict__ feat, const float* __restrict__ w_ih1,
    const float* __restrict__ w_ih2, const float* __restrict__ caption,
    const float* __restrict__ onehot,
    const float* __restrict__ b_ih1, const float* __restrict__ b_hh1,
    const float* __restrict__ b_ih2, const float* __restrict__ b_hh2,
    float* __restrict__ X1, float* __restrict__ XW2,
    float* __restrict__ bias1, float* __restrict__ bias2,
    u32* __restrict__ H1H, u32* __restrict__ H2H, u32* __restrict__ A2P,
    float* __restrict__ loss, int* __restrict__ ctrs,
    int* __restrict__ targets) {
  __shared__ __align__(16) char psm[50688];
  int blk = blockIdx.x, tid = threadIdx.x;
  if (blk < 160) {
    gemm_x1_body(psm, blk, feat, w_ih1, b_ih1, b_hh1, X1);
  } else if (blk < 1088) {
    int k = blk - 160;  // (s-1)*32 + b
    int s = (k >> 5) + 1, b = k & 31;
    const float* row = &onehot[((size_t)b * TD + s) * VV];
    float bv = -INFINITY;
    int bi = 0x7fffffff;
    for (int v = tid; v < VV; v += 256) {
      float x = row[v];
      if (x > bv || (x == bv && v < bi)) { bv = x; bi = v; }
    }
    float* sv = (float*)psm;
    int* si = (int*)(psm + 1024);
    sv[tid] = bv; si[tid] = bi;
    __syncthreads();
    for (int off = 128; off; off >>= 1) {
      if (tid < off) {
        float ov = sv[tid + off]; int oi = si[tid + off];
        if (ov > sv[tid] || (ov == sv[tid] && oi < si[tid])) { sv[tid] = ov; si[tid] = oi; }
      }
      __syncthreads();
    }
    if (tid == 0) targets[k] = si[0];
  } else if (blk < 1552) {
    // XW2[(t*32+b)][n] = bf16(caption[b][t][:]) . bf16(w_ih2[n][0:256]) + bias2[n]
    int k = blk - 1088, nb = k & 15, t = k >> 4;
    u16* As = (u16*)psm;                 // [32][264]
    u16* Bs = (u16*)(psm + 16896);       // [64][264]
    int nBase = nb * 64;
#pragma unroll
    for (int it = 0; it < 4; ++it) {
      int i = it * 256 + tid;
      int r = i >> 5, c8 = i & 31;
      const float* src = &caption[((size_t)r * TD + t) * 256 + c8 * 8];
      float4 v0 = *(const float4*)src;
      float4 v1 = *(const float4*)(src + 4);
      u16* dst = &As[r * 264 + c8 * 8];
      *(ushort4*)dst = make_ushort4(f2bf(v0.x), f2bf(v0.y), f2bf(v0.z), f2bf(v0.w));
      *(ushort4*)(dst + 4) = make_ushort4(f2bf(v1.x), f2bf(v1.y), f2bf(v1.z), f2bf(v1.w));
    }
#pragma unroll
    for (int it = 0; it < 8; ++it) {
      int i = it * 256 + tid;
      int r = i >> 5, c8 = i & 31;
      const float* src = &w_ih2[(size_t)(nBase + r) * 512 + c8 * 8];
      float4 v0 = *(const float4*)src;
      float4 v1 = *(const float4*)(src + 4);
      u16* dst = &Bs[r * 264 + c8 * 8];
      *(ushort4*)dst = make_ushort4(f2bf(v0.x), f2bf(v0.y), f2bf(v0.z), f2bf(v0.w));
      *(ushort4*)(dst + 4) = make_ushort4(f2bf(v1.x), f2bf(v1.y), f2bf(v1.z), f2bf(v1.w));
    }
    __syncthreads();
    int lane = tid & 63, w = tid >> 6;
    int lrow = lane & 15, lk = (lane >> 4) * 8;
    f32x4 acc[2];
    acc[0] = (f32x4){0.f, 0.f, 0.f, 0.f};
    acc[1] = (f32x4){0.f, 0.f, 0.f, 0.f};
#pragma unroll
    for (int ks = 0; ks < 8; ++ks) {
      bf16x8 bfr = *(const bf16x8*)&Bs[(w * 16 + lrow) * 264 + ks * 32 + lk];
#pragma unroll
      for (int m = 0; m < 2; ++m) {
        bf16x8 af = *(const bf16x8*)&As[(m * 16 + lrow) * 264 + ks * 32 + lk];
        acc[m] = __builtin_amdgcn_mfma_f32_16x16x32_bf16(af, bfr, acc[m], 0, 0, 0);
      }
    }
    int col = nBase + w * 16 + (lane & 15);
    float bv = b_ih2[col] + b_hh2[col];
    int orow = (lane >> 4) * 4;
#pragma unroll
    for (int m = 0; m < 2; ++m)
#pragma unroll
      for (int qq = 0; qq < 4; ++qq) {
        int bb = m * 16 + orow + qq;
        XW2[((size_t)t * 32 + bb) * G4 + col] = acc[m][qq] + bv;
      }
  } else if (blk < 1992) {
    int i = (blk - 1552) * 256 + tid;  // uint4 idx < 112640
    uint4 z = {0u, 0u, 0u, 0u};
    uint4 s = {SENT, SENT, SENT, SENT};
    uint4 v = (i < 1024) ? z : s;      // slot T=0 = packed f16 zeros
    ((uint4*)H1H)[i] = v;
    ((uint4*)H2H)[i] = v;
  } else if (blk < 2432) {
    int i0 = (blk - 1992) * 1024 + tid;  // uint4 idx < 450560
    uint4 s = {SENT, SENT, SENT, SENT};
#pragma unroll
    for (int ii = 0; ii < 4; ++ii) ((uint4*)A2P)[i0 + ii * 256] = s;
  } else {
    for (int i = tid; i < 1024; i += 256) {
      bias1[i] = b_ih1[i] + b_hh1[i];
      bias2[i] = b_ih2[i] + b_hh2[i];
    }
    if (tid < 256) ctrs[tid] = 0;
    if (tid == 0) *loss = 0.0f;
  }
}

// ===========================================================================
// Persistent recurrent kernel (r14-proven; packed A2P).
// 256 blocks x 512 threads. L1 [0,128): h1 chain (wA) + a2p (wB), publish
// packed pairs. L2B [128,256): h2 chain (wC only), encL history, attention.
// ===========================================================================
struct RP {
  const float *X1, *XW2, *bias1, *bias2;
  const float *w_hh1, *w_ih2, *w_hh2;
  u32* H1H;     // [110][32][128] packed f16x2 of h1[T]
  u32* H2H;     // [110][32][128] packed f16x2 of h2[U]
  u32* A2P;     // [110][32][512] packed f16x2 pairs of a2 rows
  u16* H2NB;    // [29][32][256] bf16 decoder h2n
};

__global__ __launch_bounds__(512, 1) void recurrent_kernel(RP p) {
  __shared__ float encL[TE][257];             // 82 KB (L2B only)
  __shared__ __align__(16) f16x2 hS[128];
  __shared__ float tmp2[256];
  __shared__ float gb[256];
  __shared__ float a2pS[256];
  __shared__ float hnew[64];
  __shared__ float sc[80];
  __shared__ float red[4];
  int bid = blockIdx.x, tid = threadIdx.x;
  bool isL1 = bid < 128;
  int lb = isL1 ? bid : bid - 128;
  int b = lb >> 2, q = lb & 3;
  int r2 = tid >> 1, half = tid & 1;
  int g = r2 >> 6, jj = r2 & 63;
  int grow = (g << 8) + (q << 6) + jj;
  int jf = (q << 6) + tid;  // valid for tid<64

  if (isL1) {
    f16x2 wA[64], wB[64];
    {
      const float4* sA = (const float4*)(p.w_hh1 + (size_t)grow * 256 + half * 128);
      const float4* sB = (const float4*)(p.w_ih2 + (size_t)grow * 512 + 256 + half * 128);
#pragma unroll
      for (int k = 0; k < 32; ++k) {
        float4 v = sA[k];
        wA[k * 2 + 0] = f16x2{(_Float16)v.x, (_Float16)v.y};
        wA[k * 2 + 1] = f16x2{(_Float16)v.z, (_Float16)v.w};
        float4 u = sB[k];
        wB[k * 2 + 0] = f16x2{(_Float16)u.x, (_Float16)u.y};
        wB[k * 2 + 1] = f16x2{(_Float16)u.z, (_Float16)u.w};
      }
    }
    float c1 = 0.f;
    float b1v0 = 0, b1v1 = 0, b1v2 = 0, b1v3 = 0;
    if (tid < 64) {
      b1v0 = p.bias1[jf]; b1v1 = p.bias1[256 + jf];
      b1v2 = p.bias1[512 + jf]; b1v3 = p.bias1[768 + jf];
    }
    for (int T = 0; T <= 109; ++T) {
      float x0 = b1v0, x1 = b1v1, x2 = b1v2, x3 = b1v3;
      if (tid < 64 && T < TE) {
        const float* xb = &p.X1[((size_t)b * TE + T) * G4 + jf];
        x0 = xb[0]; x1 = xb[256]; x2 = xb[512]; x3 = xb[768];
      }
      if (tid < 128) {
        const u32* src = &p.H1H[((size_t)T * 32 + b) * 128 + tid];
        u32 v = AT_LOAD(src);
        int gd = 0;
        while (v == SENT && ++gd < GUARD) {
          __builtin_amdgcn_s_sleep(1);
          v = AT_LOAD(src);
        }
        hS[tid] = __builtin_bit_cast(f16x2, v);
      }
      __syncthreads();  // S1
      float a1 = 0.f, a2 = 0.f;
      {
        const uint4* hv = ((const uint4*)hS) + half * 16;
#pragma unroll
        for (int k = 0; k < 16; ++k) {
          uint4 uu = hv[k];
          f16x2 e0 = __builtin_bit_cast(f16x2, uu.x), e1 = __builtin_bit_cast(f16x2, uu.y);
          f16x2 e2 = __builtin_bit_cast(f16x2, uu.z), e3 = __builtin_bit_cast(f16x2, uu.w);
          a1 = fdot2h(e0, wA[k * 4 + 0], a1);
          a2 = fdot2h(e0, wB[k * 4 + 0], a2);
          a1 = fdot2h(e1, wA[k * 4 + 1], a1);
          a2 = fdot2h(e1, wB[k * 4 + 1], a2);
          a1 = fdot2h(e2, wA[k * 4 + 2], a1);
          a2 = fdot2h(e2, wB[k * 4 + 2], a2);
          a1 = fdot2h(e3, wA[k * 4 + 3], a1);
          a2 = fdot2h(e3, wB[k * 4 + 3], a2);
        }
      }
      a1 += __shfl_xor(a1, 1);
      a2 += __shfl_xor(a2, 1);
      float a2o = __shfl_xor(a2, 2);  // partner row's a2
      if (half == 0) gb[r2] = a1;
      if ((tid & 3) == 0 && T >= 1) {
        int pr = tid >> 2;  // pair 0..127
        int gp = pr >> 5, wp = pr & 31;
        AT_STORE(&p.A2P[((size_t)T * 32 + b) * 512 + (gp << 7) + (q << 5) + wp],
                 packh2(a2, a2o));
      }
      __syncthreads();  // S2
      if (T <= 108) {
        if (tid < 64) {
          float gi = gb[tid] + x0;
          float gf = gb[64 + tid] + x1;
          float gG = gb[128 + tid] + x2;
          float go = gb[192 + tid] + x3;
          c1 = sigm(gf) * c1 + sigm(gi) * tanhf(gG);
          hnew[tid] = sigm(go) * tanhf(c1);
        }
        if (tid < 32) {  // same wave as hnew writers
          u32 pk = packh2(hnew[2 * tid], hnew[2 * tid + 1]);
          AT_STORE(&p.H1H[((size_t)(T + 1) * 32 + b) * 128 + (q << 5) + tid], pk);
        }
      }
    }
  } else {
    f16x2 wC[64];
    {
      const float4* sC = (const float4*)(p.w_hh2 + (size_t)grow * 256 + half * 128);
#pragma unroll
      for (int k = 0; k < 32; ++k) {
        float4 u = sC[k];
        wC[k * 2 + 0] = f16x2{(_Float16)u.x, (_Float16)u.y};
        wC[k * 2 + 1] = f16x2{(_Float16)u.z, (_Float16)u.w};
      }
    }
    float c2 = 0.f;
    float b2v0 = 0, b2v1 = 0, b2v2 = 0, b2v3 = 0;
    if (tid < 64) {
      b2v0 = p.bias2[jf]; b2v1 = p.bias2[256 + jf];
      b2v2 = p.bias2[512 + jf]; b2v3 = p.bias2[768 + jf];
    }
    for (int U = 1; U <= 109; ++U) {
      float x0 = b2v0, x1 = b2v1, x2 = b2v2, x3 = b2v3;
      if (tid < 64 && U >= 81) {
        const float* xb = &p.XW2[((size_t)(U - 81) * 32 + b) * G4 + jf];
        x0 = xb[0]; x1 = xb[256]; x2 = xb[512]; x3 = xb[768];  // bias folded
      }
      // concurrent polls: h2[U-1] (pure spin) and packed a2p[U]
      if (tid < 128) {
        const u32* src = &p.H2H[((size_t)(U - 1) * 32 + b) * 128 + tid];
        u32 v = AT_LOAD(src);
        int gd = 0;
        while (v == SENT && ++gd < (GUARD << 2)) v = AT_LOAD(src);
        f16x2 hp = __builtin_bit_cast(f16x2, v);
        hS[tid] = hp;
        tmp2[2 * tid] = (float)hp[0];
        tmp2[2 * tid + 1] = (float)hp[1];
      } else if (tid < 256) {
        int rr = tid - 128;
        int gp = rr >> 5, wp = rr & 31;
        const u32* src = &p.A2P[((size_t)U * 32 + b) * 512 + (gp << 7) + (q << 5) + wp];
        u32 v = AT_LOAD(src);
        int gd = 0;
        while (v == SENT && ++gd < GUARD) {
          __builtin_amdgcn_s_sleep(1);
          v = AT_LOAD(src);
        }
        f16x2 pr = __builtin_bit_cast(f16x2, v);
        a2pS[gp * 64 + 2 * wp] = (float)pr[0];
        a2pS[gp * 64 + 2 * wp + 1] = (float)pr[1];
      }
      __syncthreads();  // S1
      float a2p0 = 0, a2p1 = 0, a2p2 = 0, a2p3 = 0;
      if (tid < 64) {
        a2p0 = a2pS[tid]; a2p1 = a2pS[64 + tid];
        a2p2 = a2pS[128 + tid]; a2p3 = a2pS[192 + tid];
      }
      if (U <= 81) {
        if (U >= 2 && tid < 256) encL[U - 2][tid] = tmp2[tid];
      } else {
        // attention: q-vec = tmp2 (h2n[s-1]); parallel softmax; ctx -> hS
        float a = 0.f;
        if (tid < TE) {
          const float* e = &encL[tid][0];
#pragma unroll 8
          for (int k2 = 0; k2 < 256; ++k2) a += e[k2] * tmp2[k2];
        }
        float av = (tid < TE) ? a : -INFINITY;
#pragma unroll
        for (int d = 32; d; d >>= 1) av = fmaxf(av, __shfl_xor(av, d));
        if (tid == 0) red[0] = av;
        if (tid == 64) red[1] = av;
        __syncthreads();
        float m = fmaxf(red[0], red[1]);
        float e2 = (tid < TE) ? expf(a - m) : 0.f;
        float sv = e2;
#pragma unroll
        for (int d = 32; d; d >>= 1) sv += __shfl_xor(sv, d);
        if (tid == 0) red[2] = sv;
        if (tid == 64) red[3] = sv;
        __syncthreads();
        float inv = 1.0f / (red[2] + red[3]);
        if (tid < TE) sc[tid] = e2 * inv;
        __syncthreads();
        if (tid < 256) {
          float acc = 0.f;
          for (int t2 = 0; t2 < TE; ++t2) acc += sc[t2] * encL[t2][tid];
          tmp2[tid] = acc;
        }
        __syncthreads();
        if (tid < 128)
          hS[tid] = f16x2{(_Float16)tmp2[2 * tid], (_Float16)tmp2[2 * tid + 1]};
      }
      __syncthreads();
      float a2 = 0.f;
      {
        const uint4* hv = ((const uint4*)hS) + half * 16;
#pragma unroll
        for (int k = 0; k < 16; ++k) {
          uint4 uu = hv[k];
          a2 = fdot2h(__builtin_bit_cast(f16x2, uu.x), wC[k * 4 + 0], a2);
          a2 = fdot2h(__builtin_bit_cast(f16x2, uu.y), wC[k * 4 + 1], a2);
          a2 = fdot2h(__builtin_bit_cast(f16x2, uu.z), wC[k * 4 + 2], a2);
          a2 = fdot2h(__builtin_bit_cast(f16x2, uu.w), wC[k * 4 + 3], a2);
        }
      }
      a2 += __shfl_xor(a2, 1);
      if (half == 0) gb[r2] = a2;
      __syncthreads();
      if (tid < 64) {
        float gi = gb[tid] + a2p0 + x0;
        float gf = gb[64 + tid] + a2p1 + x1;
        float gG = gb[128 + tid] + a2p2 + x2;
        float go = gb[192 + tid] + a2p3 + x3;
        c2 = sigm(gf) * c2 + sigm(gi) * tanhf(gG);
        float h = sigm(go) * tanhf(c2);
        hnew[tid] = h;
        if (U >= 81)
          p.H2NB[((size_t)(U - 81) * 32 + b) * 256 + jf] = f2bf(h);
      }
      if (tid < 32) {  // same wave as hnew writers
        u32 pk = packh2(hnew[2 * tid], hnew[2 * tid + 1]);
        AT_STORE(&p.H2H[((size_t)U * 32 + b) * 128 + (q << 5) + tid], pk);
      }
    }
  }
}

// ===========================================================================
// Fused logits + CE partials + final reduce (250 co-resident blocks).
// ===========================================================================
__global__ __launch_bounds__(256, 1) void logits_final_kernel(
    const u16* __restrict__ H2NB, const float* __restrict__ w_out,
    const float* __restrict__ b_out, const int* __restrict__ targets,
    u32* __restrict__ pmaxA, u32* __restrict__ psumA, u32* __restrict__ tgtv,
    float* __restrict__ loss, int* __restrict__ ctrs, float* __restrict__ out) {
  __shared__ __align__(16) u16 bS[32768];
  __shared__ __align__(16) u16 aS[32 * 264];
  __shared__ int tS[32];
  __shared__ float sm[256];
  int tid = threadIdx.x, bid = blockIdx.x;
#pragma unroll
  for (int it = 0; it < 16; ++it) {
    int id = it * 256 + tid;
    int nt = id >> 9, rr = (id >> 5) & 15, kg = id & 31;
    int n = bid * 128 + nt * 16 + rr;
    const float* src = &w_out[(size_t)n * 256 + kg * 8];
    float4 v0 = *(const float4*)src;
    float4 v1 = *(const float4*)(src + 4);
    u16* dst = &bS[(size_t)((nt * 32 + kg) * 16 + rr) * 8];
    *(ushort4*)dst = make_ushort4(f2bf(v0.x), f2bf(v0.y), f2bf(v0.z), f2bf(v0.w));
    *(ushort4*)(dst + 4) = make_ushort4(f2bf(v1.x), f2bf(v1.y), f2bf(v1.z), f2bf(v1.w));
  }
  int wid = tid >> 6, lane = tid & 63, lcol = lane & 15, lk = lane >> 4;
  float bo[2];
#pragma unroll
  for (int n = 0; n < 2; ++n) bo[n] = b_out[(bid * 8 + wid * 2 + n) * 16 + lcol];

  for (int rg = 0; rg < 29; ++rg) {
    __syncthreads();
    for (int i = tid; i < 1024; i += 256) {
      int r = i >> 5, c8 = i & 31;
      *(uint4*)&aS[r * 264 + c8 * 8] =
          *(const uint4*)&H2NB[(size_t)rg * 8192 + r * 256 + c8 * 8];
    }
    if (tid < 32) tS[tid] = targets[rg * 32 + tid];
    __syncthreads();
    f32x4 acc[2][2];
#pragma unroll
    for (int m = 0; m < 2; ++m)
#pragma unroll
      for (int n = 0; n < 2; ++n) acc[m][n] = (f32x4){0.f, 0.f, 0.f, 0.f};
#pragma unroll
    for (int ks = 0; ks < 8; ++ks) {
      bf16x8 a0 = *(const bf16x8*)&aS[lcol * 264 + ks * 32 + lk * 8];
      bf16x8 a1 = *(const bf16x8*)&aS[(16 + lcol) * 264 + ks * 32 + lk * 8];
      bf16x8 b0 = *(const bf16x8*)&bS[(wid * 2) * 4096 + ((ks * 4 + lk) * 16 + lcol) * 8];
      bf16x8 b1 = *(const bf16x8*)&bS[(wid * 2 + 1) * 4096 + ((ks * 4 + lk) * 16 + lcol) * 8];
      acc[0][0] = __builtin_amdgcn_mfma_f32_16x16x32_bf16(a0, b0, acc[0][0], 0, 0, 0);
      acc[0][1] = __builtin_amdgcn_mfma_f32_16x16x32_bf16(a0, b1, acc[0][1], 0, 0, 0);
      acc[1][0] = __builtin_amdgcn_mfma_f32_16x16x32_bf16(a1, b0, acc[1][0], 0, 0, 0);
      acc[1][1] = __builtin_amdgcn_mfma_f32_16x16x32_bf16(a1, b1, acc[1][1], 0, 0, 0);
    }
    int nbase = (bid * 8 + wid * 2) * 16 + lcol;
#pragma unroll
    for (int m = 0; m < 2; ++m) {
      float pm[4], psv[4];
#pragma unroll
      for (int qq = 0; qq < 4; ++qq) {
        float v0 = acc[m][0][qq] + bo[0];
        float v1 = acc[m][1][qq] + bo[1];
        int r = m * 16 + lk * 4 + qq;
        int tg = tS[r];
        if (tg == nbase) AT_STORE(&tgtv[rg * 32 + r], __float_as_uint(v0));
        if (tg == nbase + 16) AT_STORE(&tgtv[rg * 32 + r], __float_as_uint(v1));
        float mx = fmaxf(v0, v1);
#pragma unroll
        for (int d = 1; d < 16; d <<= 1) mx = fmaxf(mx, __shfl_xor(mx, d));
        float e = expf(v0 - mx) + expf(v1 - mx);
#pragma unroll
        for (int d = 1; d < 16; d <<= 1) e += __shfl_xor(e, d);
        pm[qq] = mx;
        psv[qq] = e;
      }
      if (lcol == 0) {
        int chunk = bid * 4 + wid;
#pragma unroll
        for (int qq = 0; qq < 4; ++qq) {
          int r2 = rg * 32 + m * 16 + lk * 4 + qq;
          AT_STORE(&pmaxA[(size_t)r2 * 1000 + chunk], __float_as_uint(pm[qq]));
          AT_STORE(&psumA[(size_t)r2 * 1000 + chunk], __float_as_uint(psv[qq]));
        }
      }
    }
  }
  asm volatile("s_waitcnt vmcnt(0)" ::: "memory");
  __syncthreads();
  if (tid == 0) {
    __hip_atomic_fetch_add(&ctrs[0], 1, __ATOMIC_RELEASE, __HIP_MEMORY_SCOPE_AGENT);
    int gd = 0;
    while (__hip_atomic_load(&ctrs[0], __ATOMIC_ACQUIRE, __HIP_MEMORY_SCOPE_AGENT) < 250 &&
           ++gd < GUARD)
      __builtin_amdgcn_s_sleep(2);
  }
  __syncthreads();
#pragma unroll
  for (int k = 0; k < 4; ++k) {
    int row = bid * 4 + k;
    if (row < 928) {
      const u32* pm = pmaxA + (size_t)row * 1000;
      const u32* psv = psumA + (size_t)row * 1000;
      float m = -INFINITY;
      for (int c = tid; c < 1000; c += 256) m = fmaxf(m, __uint_as_float(AT_LOAD(&pm[c])));
      sm[tid] = m;
      __syncthreads();
      for (int off = 128; off; off >>= 1) {
        if (tid < off) sm[tid] = fmaxf(sm[tid], sm[tid + off]);
        __syncthreads();
      }
      float M = sm[0];
      __syncthreads();
      float s = 0.f;
      for (int c = tid; c < 1000; c += 256)
        s += __uint_as_float(AT_LOAD(&psv[c])) * expf(__uint_as_float(AT_LOAD(&pm[c])) - M);
      sm[tid] = s;
      __syncthreads();
      for (int off = 128; off; off >>= 1) {
        if (tid < off) sm[tid] += sm[tid + off];
        __syncthreads();
      }
      if (tid == 0) {
        float tv = __uint_as_float(AT_LOAD(&tgtv[row]));
        atomicAdd(loss, (M + logf(sm[0]) - tv) * (1.0f / 1024.0f));
      }
      __syncthreads();
    }
  }
  asm volatile("s_waitcnt vmcnt(0)" ::: "memory");
  if (tid == 0) {
    int old = __hip_atomic_fetch_add(&ctrs[32], 1, __ATOMIC_ACQ_REL, __HIP_MEMORY_SCOPE_AGENT);
    if (old == 249) out[0] = __uint_as_float(AT_LOAD((u32*)loss));
  }
}

// ---------------------------------------------------------------------------
extern "C" void kernel_launch(void* const* d_in, const int* in_sizes, int n_in,
                              void* d_out, int out_size, void* d_ws, size_t ws_size,
                              hipStream_t stream) {
  (void)in_sizes; (void)n_in; (void)out_size; (void)ws_size;
  const float* feat    = (const float*)d_in[0];
  const float* caption = (const float*)d_in[1];
  const float* onehot  = (const float*)d_in[2];
  const float* w_ih1   = (const float*)d_in[4];
  const float* w_hh1   = (const float*)d_in[5];
  const float* b_ih1   = (const float*)d_in[6];
  const float* b_hh1   = (const float*)d_in[7];
  const float* w_ih2   = (const float*)d_in[8];
  const float* w_hh2   = (const float*)d_in[9];
  const float* b_ih2   = (const float*)d_in[10];
  const float* b_hh2   = (const float*)d_in[11];
  const float* w_out   = (const float*)d_in[12];
  const float* b_out   = (const float*)d_in[13];

  char* p = (char*)d_ws;
  auto alloc = [&](size_t bytes) {
    char* r = p;
    p += (bytes + 255) & ~(size_t)255;
    return r;
  };
  float* X1      = (float*)alloc(2560ull * 1024 * 4);    // 10.5 MB
  float* XW2     = (float*)alloc(29ull * 32 * 1024 * 4); // 3.8 MB
  float* bias1   = (float*)alloc(1024 * 4);
  float* bias2   = (float*)alloc(1024 * 4);
  u32*   H1H     = (u32*)alloc(110ull * 32 * 128 * 4);   // 1.8 MB
  u32*   H2H     = (u32*)alloc(110ull * 32 * 128 * 4);   // 1.8 MB
  u32*   A2P     = (u32*)alloc(110ull * 32 * 512 * 4);   // 7.2 MB
  u16*   H2NB    = (u16*)alloc(29ull * 8192 * 2);
  u32*   pmaxA   = (u32*)alloc(928ull * 1000 * 4);
  u32*   psumA   = (u32*)alloc(928ull * 1000 * 4);
  u32*   tgtv    = (u32*)alloc(928 * 4);
  float* lossacc = (float*)alloc(256);
  int*   ctrs    = (int*)alloc(1024);
  int*   targets = (int*)alloc(29 * 32 * 4);

  prepall_kernel<<<2433, 256, 0, stream>>>(
      feat, w_ih1, w_ih2, caption, onehot,
      b_ih1, b_hh1, b_ih2, b_hh2,
      X1, XW2, bias1, bias2, H1H, H2H, A2P, lossacc, ctrs, targets);

  RP rp;
  rp.X1 = X1; rp.XW2 = XW2; rp.bias1 = bias1; rp.bias2 = bias2;
  rp.w_hh1 = w_hh1; rp.w_ih2 = w_ih2; rp.w_hh2 = w_hh2;
  rp.H1H = H1H; rp.H2H = H2H; rp.A2P = A2P; rp.H2NB = H2NB;
  void* args[] = {&rp};
  hipLaunchCooperativeKernel((const void*)recurrent_kernel, dim3(256), dim3(512),
                             args, 0, stream);

  logits_final_kernel<<<250, 256, 0, stream>>>(H2NB, w_out, b_out, targets,
                                               pmaxA, psumA, tgtv, lossacc, ctrs,
                                               (float*)d_out);
}

// Round 17
// 748.406 us; speedup vs baseline: 1.6177x; 1.1982x over previous
//
#include <hip/hip_runtime.h>
#include <hip/hip_bf16.h>
#include <math.h>

// Problem dims
#define BB 32
#define TE 80
#define FEAT 4096
#define HH 256
#define W2V 256
#define TD 30
#define VV 32000
#define G4 1024   // 4*H

typedef unsigned short u16;
typedef unsigned int u32;
using f32x4 = __attribute__((ext_vector_type(4))) float;
using bf16x8 = __attribute__((ext_vector_type(8))) short;
using f16x2 = __attribute__((ext_vector_type(2))) _Float16;

#define SENT 0xFFFFFFFFu
#define GUARD (1 << 22)

__device__ __forceinline__ float sigm(float x) { return 1.0f / (1.0f + expf(-x)); }
__device__ __forceinline__ u16 f2bf(float f) {
  u32 u = __float_as_uint(f);
  u32 r = (u + 0x7FFFu + ((u >> 16) & 1u)) >> 16;
  return (u16)r;
}
__device__ __forceinline__ u32 packh2(float lo, float hi) {
  f16x2 v = {(_Float16)lo, (_Float16)hi};
  return __builtin_bit_cast(u32, v);
}

#define AT_LOAD(p)     __hip_atomic_load((p), __ATOMIC_RELAXED, __HIP_MEMORY_SCOPE_AGENT)
#define AT_STORE(p, v) __hip_atomic_store((p), (v), __ATOMIC_RELAXED, __HIP_MEMORY_SCOPE_AGENT)

__device__ __forceinline__ float fdot2h(f16x2 a, f16x2 b, float c) {
#if __has_builtin(__builtin_amdgcn_fdot2)
  return __builtin_amdgcn_fdot2(a, b, c, false);
#else
  return c + (float)a[0] * (float)b[0] + (float)a[1] * (float)b[1];
#endif
}

// ===========================================================================
// gemm_x1 (standalone launch; f32 inputs, inline cvt; bias from raw inputs)
// ===========================================================================
#define GBM 128
#define GBN 128
#define GBK 64
#define LDSTR 72

__global__ __launch_bounds__(256) void gemm_x1_kernel(
    const float* __restrict__ A, const float* __restrict__ Bw,
    const float* __restrict__ b_ih1, const float* __restrict__ b_hh1,
    float* __restrict__ C) {
  __shared__ __align__(16) u16 As[GBM * LDSTR];
  __shared__ __align__(16) u16 Bs[GBN * LDSTR];
  int tid = threadIdx.x;
  int rBase = (blockIdx.x >> 3) * GBM;
  int nBase = (blockIdx.x & 7) * GBN;
  int lane = tid & 63, w = tid >> 6;
  int wrow = (w >> 1) * 64, wcol = (w & 1) * 64;
  int lrow = lane & 15, lk = (lane >> 4) * 8;

  f32x4 acc[4][4];
#pragma unroll
  for (int m = 0; m < 4; ++m)
#pragma unroll
    for (int n = 0; n < 4; ++n) acc[m][n] = (f32x4){0.f, 0.f, 0.f, 0.f};

  for (int k0 = 0; k0 < FEAT; k0 += GBK) {
#pragma unroll
    for (int i = 0; i < 8; ++i) {
      int f = i * 256 + tid;
      int r = f >> 4, c = (f & 15) << 2;
      float4 v = *(const float4*)&A[(size_t)(rBase + r) * FEAT + k0 + c];
      *(ushort4*)&As[r * LDSTR + c] =
          make_ushort4(f2bf(v.x), f2bf(v.y), f2bf(v.z), f2bf(v.w));
    }
#pragma unroll
    for (int i = 0; i < 8; ++i) {
      int f = i * 256 + tid;
      int r = f >> 4, c = (f & 15) << 2;
      float4 v = *(const float4*)&Bw[(size_t)(nBase + r) * FEAT + k0 + c];
      *(ushort4*)&Bs[r * LDSTR + c] =
          make_ushort4(f2bf(v.x), f2bf(v.y), f2bf(v.z), f2bf(v.w));
    }
    __syncthreads();
#pragma unroll
    for (int s2 = 0; s2 < 2; ++s2) {
      bf16x8 af[4], bfr[4];
#pragma unroll
      for (int m = 0; m < 4; ++m)
        af[m] = *(const bf16x8*)&As[(wrow + m * 16 + lrow) * LDSTR + s2 * 32 + lk];
#pragma unroll
      for (int n = 0; n < 4; ++n)
        bfr[n] = *(const bf16x8*)&Bs[(wcol + n * 16 + lrow) * LDSTR + s2 * 32 + lk];
#pragma unroll
      for (int m = 0; m < 4; ++m)
#pragma unroll
        for (int n = 0; n < 4; ++n)
          acc[m][n] = __builtin_amdgcn_mfma_f32_16x16x32_bf16(
              af[m], bfr[n], acc[m][n], 0, 0, 0);
    }
    __syncthreads();
  }
  int orow = (lane >> 4) * 4;
  int ocol = lane & 15;
#pragma unroll
  for (int m = 0; m < 4; ++m)
#pragma unroll
    for (int n = 0; n < 4; ++n) {
      int cidx = nBase + wcol + n * 16 + ocol;
      float bv = b_ih1[cidx] + b_hh1[cidx];
#pragma unroll
      for (int q = 0; q < 4; ++q) {
        int r = rBase + wrow + m * 16 + orow + q;
        C[(size_t)r * G4 + cidx] = acc[m][n][q] + bv;
      }
    }
}

// ===========================================================================
// prep: argmax | XW2 MFMA (inline cvt, +bias) | H sentinels | A2P sentinels |
// bias+misc.  blocks: [0,928) | [928,1392) | [1392,1832) | [1832,2272) | 2272
// ===========================================================================
__global__ __launch_bounds__(256) void prep_kernel(
    const float* __restrict__ w_ih2, const float* __restrict__ caption,
    const float* __restrict__ onehot,
    const float* __restrict__ b_ih1, const float* __restrict__ b_hh1,
    const float* __restrict__ b_ih2, const float* __restrict__ b_hh2,
    float* __restrict__ XW2,
    float* __restrict__ bias1, float* __restrict__ bias2,
    u32* __restrict__ H1H, u32* __restrict__ H2H, u32* __restrict__ A2P,
    float* __restrict__ loss, int* __restrict__ ctrs,
    int* __restrict__ targets) {
  __shared__ __align__(16) char psm[50688];
  int blk = blockIdx.x, tid = threadIdx.x;
  if (blk < 928) {
    int k = blk;  // (s-1)*32 + b
    int s = (k >> 5) + 1, b = k & 31;
    const float* row = &onehot[((size_t)b * TD + s) * VV];
    float bv = -INFINITY;
    int bi = 0x7fffffff;
    for (int v = tid; v < VV; v += 256) {
      float x = row[v];
      if (x > bv || (x == bv && v < bi)) { bv = x; bi = v; }
    }
    float* sv = (float*)psm;
    int* si = (int*)(psm + 1024);
    sv[tid] = bv; si[tid] = bi;
    __syncthreads();
    for (int off = 128; off; off >>= 1) {
      if (tid < off) {
        float ov = sv[tid + off]; int oi = si[tid + off];
        if (ov > sv[tid] || (ov == sv[tid] && oi < si[tid])) { sv[tid] = ov; si[tid] = oi; }
      }
      __syncthreads();
    }
    if (tid == 0) targets[k] = si[0];
  } else if (blk < 1392) {
    // XW2[(t*32+b)][n] = bf16(caption[b][t][:]) . bf16(w_ih2[n][0:256]) + bias2[n]
    int k = blk - 928, nb = k & 15, t = k >> 4;
    u16* As = (u16*)psm;                 // [32][264]
    u16* Bs = (u16*)(psm + 16896);       // [64][264]
    int nBase = nb * 64;
#pragma unroll
    for (int it = 0; it < 4; ++it) {
      int i = it * 256 + tid;
      int r = i >> 5, c8 = i & 31;
      const float* src = &caption[((size_t)r * TD + t) * 256 + c8 * 8];
      float4 v0 = *(const float4*)src;
      float4 v1 = *(const float4*)(src + 4);
      u16* dst = &As[r * 264 + c8 * 8];
      *(ushort4*)dst = make_ushort4(f2bf(v0.x), f2bf(v0.y), f2bf(v0.z), f2bf(v0.w));
      *(ushort4*)(dst + 4) = make_ushort4(f2bf(v1.x), f2bf(v1.y), f2bf(v1.z), f2bf(v1.w));
    }
#pragma unroll
    for (int it = 0; it < 8; ++it) {
      int i = it * 256 + tid;
      int r = i >> 5, c8 = i & 31;
      const float* src = &w_ih2[(size_t)(nBase + r) * 512 + c8 * 8];
      float4 v0 = *(const float4*)src;
      float4 v1 = *(const float4*)(src + 4);
      u16* dst = &Bs[r * 264 + c8 * 8];
      *(ushort4*)dst = make_ushort4(f2bf(v0.x), f2bf(v0.y), f2bf(v0.z), f2bf(v0.w));
      *(ushort4*)(dst + 4) = make_ushort4(f2bf(v1.x), f2bf(v1.y), f2bf(v1.z), f2bf(v1.w));
    }
    __syncthreads();
    int lane = tid & 63, w = tid >> 6;
    int lrow = lane & 15, lk = (lane >> 4) * 8;
    f32x4 acc[2];
    acc[0] = (f32x4){0.f, 0.f, 0.f, 0.f};
    acc[1] = (f32x4){0.f, 0.f, 0.f, 0.f};
#pragma unroll
    for (int ks = 0; ks < 8; ++ks) {
      bf16x8 bfr = *(const bf16x8*)&Bs[(w * 16 + lrow) * 264 + ks * 32 + lk];
#pragma unroll
      for (int m = 0; m < 2; ++m) {
        bf16x8 af = *(const bf16x8*)&As[(m * 16 + lrow) * 264 + ks * 32 + lk];
        acc[m] = __builtin_amdgcn_mfma_f32_16x16x32_bf16(af, bfr, acc[m], 0, 0, 0);
      }
    }
    int col = nBase + w * 16 + (lane & 15);
    float bv = b_ih2[col] + b_hh2[col];
    int orow = (lane >> 4) * 4;
#pragma unroll
    for (int m = 0; m < 2; ++m)
#pragma unroll
      for (int qq = 0; qq < 4; ++qq) {
        int bb = m * 16 + orow + qq;
        XW2[((size_t)t * 32 + bb) * G4 + col] = acc[m][qq] + bv;
      }
  } else if (blk < 1832) {
    int i = (blk - 1392) * 256 + tid;  // uint4 idx < 112640
    uint4 z = {0u, 0u, 0u, 0u};
    uint4 s = {SENT, SENT, SENT, SENT};
    uint4 v = (i < 1024) ? z : s;      // slot T=0 = packed f16 zeros
    ((uint4*)H1H)[i] = v;
    ((uint4*)H2H)[i] = v;
  } else if (blk < 2272) {
    int i = (blk - 1832) * 256 + tid;  // uint4 idx < 112640 (A2P packed, 7.2MB)
    uint4 s = {SENT, SENT, SENT, SENT};
    ((uint4*)A2P)[i] = s;
    ((uint4*)A2P)[i + 112640] = s;
    ((uint4*)A2P)[i + 225280] = s;
    ((uint4*)A2P)[i + 337920] = s;
  } else {
    for (int i = tid; i < 1024; i += 256) {
      bias1[i] = b_ih1[i] + b_hh1[i];
      bias2[i] = b_ih2[i] + b_hh2[i];
    }
    if (tid < 256) ctrs[tid] = 0;
    if (tid == 0) *loss = 0.0f;
  }
}

// ===========================================================================
// Persistent recurrent kernel (r14-proven verbatim; packed A2P).
// ===========================================================================
struct RP {
  const float *X1, *XW2, *bias1, *bias2;
  const float *w_hh1, *w_ih2, *w_hh2;
  u32* H1H;     // [110][32][128] packed f16x2 of h1[T]
  u32* H2H;     // [110][32][128] packed f16x2 of h2[U]
  u32* A2P;     // [110][32][512] packed f16x2 pairs of a2 rows
  u16* H2NB;    // [29][32][256] bf16 decoder h2n
};

__global__ __launch_bounds__(512, 1) void recurrent_kernel(RP p) {
  __shared__ float encL[TE][257];
  __shared__ __align__(16) f16x2 hS[128];
  __shared__ float tmp2[256];
  __shared__ float gb[256];
  __shared__ float a2pS[256];
  __shared__ float hnew[64];
  __shared__ float sc[80];
  __shared__ float red[4];
  int bid = blockIdx.x, tid = threadIdx.x;
  bool isL1 = bid < 128;
  int lb = isL1 ? bid : bid - 128;
  int b = lb >> 2, q = lb & 3;
  int r2 = tid >> 1, half = tid & 1;
  int g = r2 >> 6, jj = r2 & 63;
  int grow = (g << 8) + (q << 6) + jj;
  int jf = (q << 6) + tid;  // valid for tid<64

  if (isL1) {
    f16x2 wA[64], wB[64];
    {
      const float4* sA = (const float4*)(p.w_hh1 + (size_t)grow * 256 + half * 128);
      const float4* sB = (const float4*)(p.w_ih2 + (size_t)grow * 512 + 256 + half * 128);
#pragma unroll
      for (int k = 0; k < 32; ++k) {
        float4 v = sA[k];
        wA[k * 2 + 0] = f16x2{(_Float16)v.x, (_Float16)v.y};
        wA[k * 2 + 1] = f16x2{(_Float16)v.z, (_Float16)v.w};
        float4 u = sB[k];
        wB[k * 2 + 0] = f16x2{(_Float16)u.x, (_Float16)u.y};
        wB[k * 2 + 1] = f16x2{(_Float16)u.z, (_Float16)u.w};
      }
    }
    float c1 = 0.f;
    float b1v0 = 0, b1v1 = 0, b1v2 = 0, b1v3 = 0;
    if (tid < 64) {
      b1v0 = p.bias1[jf]; b1v1 = p.bias1[256 + jf];
      b1v2 = p.bias1[512 + jf]; b1v3 = p.bias1[768 + jf];
    }
    for (int T = 0; T <= 109; ++T) {
      float x0 = b1v0, x1 = b1v1, x2 = b1v2, x3 = b1v3;
      if (tid < 64 && T < TE) {
        const float* xb = &p.X1[((size_t)b * TE + T) * G4 + jf];
        x0 = xb[0]; x1 = xb[256]; x2 = xb[512]; x3 = xb[768];
      }
      if (tid < 128) {
        const u32* src = &p.H1H[((size_t)T * 32 + b) * 128 + tid];
        u32 v = AT_LOAD(src);
        int gd = 0;
        while (v == SENT && ++gd < GUARD) {
          __builtin_amdgcn_s_sleep(1);
          v = AT_LOAD(src);
        }
        hS[tid] = __builtin_bit_cast(f16x2, v);
      }
      __syncthreads();  // S1
      float a1 = 0.f, a2 = 0.f;
      {
        const uint4* hv = ((const uint4*)hS) + half * 16;
#pragma unroll
        for (int k = 0; k < 16; ++k) {
          uint4 uu = hv[k];
          f16x2 e0 = __builtin_bit_cast(f16x2, uu.x), e1 = __builtin_bit_cast(f16x2, uu.y);
          f16x2 e2 = __builtin_bit_cast(f16x2, uu.z), e3 = __builtin_bit_cast(f16x2, uu.w);
          a1 = fdot2h(e0, wA[k * 4 + 0], a1);
          a2 = fdot2h(e0, wB[k * 4 + 0], a2);
          a1 = fdot2h(e1, wA[k * 4 + 1], a1);
          a2 = fdot2h(e1, wB[k * 4 + 1], a2);
          a1 = fdot2h(e2, wA[k * 4 + 2], a1);
          a2 = fdot2h(e2, wB[k * 4 + 2], a2);
          a1 = fdot2h(e3, wA[k * 4 + 3], a1);
          a2 = fdot2h(e3, wB[k * 4 + 3], a2);
        }
      }
      a1 += __shfl_xor(a1, 1);
      a2 += __shfl_xor(a2, 1);
      float a2o = __shfl_xor(a2, 2);  // partner row's a2
      if (half == 0) gb[r2] = a1;
      if ((tid & 3) == 0 && T >= 1) {
        int pr = tid >> 2;  // pair 0..127
        int gp = pr >> 5, wp = pr & 31;
        AT_STORE(&p.A2P[((size_t)T * 32 + b) * 512 + (gp << 7) + (q << 5) + wp],
                 packh2(a2, a2o));
      }
      __syncthreads();  // S2
      if (T <= 108) {
        if (tid < 64) {
          float gi = gb[tid] + x0;
          float gf = gb[64 + tid] + x1;
          float gG = gb[128 + tid] + x2;
          float go = gb[192 + tid] + x3;
          c1 = sigm(gf) * c1 + sigm(gi) * tanhf(gG);
          hnew[tid] = sigm(go) * tanhf(c1);
        }
        if (tid < 32) {  // same wave as hnew writers
          u32 pk = packh2(hnew[2 * tid], hnew[2 * tid + 1]);
          AT_STORE(&p.H1H[((size_t)(T + 1) * 32 + b) * 128 + (q << 5) + tid], pk);
        }
      }
    }
  } else {
    f16x2 wC[64];
    {
      const float4* sC = (const float4*)(p.w_hh2 + (size_t)grow * 256 + half * 128);
#pragma unroll
      for (int k = 0; k < 32; ++k) {
        float4 u = sC[k];
        wC[k * 2 + 0] = f16x2{(_Float16)u.x, (_Float16)u.y};
        wC[k * 2 + 1] = f16x2{(_Float16)u.z, (_Float16)u.w};
      }
    }
    float c2 = 0.f;
    float b2v0 = 0, b2v1 = 0, b2v2 = 0, b2v3 = 0;
    if (tid < 64) {
      b2v0 = p.bias2[jf]; b2v1 = p.bias2[256 + jf];
      b2v2 = p.bias2[512 + jf]; b2v3 = p.bias2[768 + jf];
    }
    for (int U = 1; U <= 109; ++U) {
      float x0 = b2v0, x1 = b2v1, x2 = b2v2, x3 = b2v3;
      if (tid < 64 && U >= 81) {
        const float* xb = &p.XW2[((size_t)(U - 81) * 32 + b) * G4 + jf];
        x0 = xb[0]; x1 = xb[256]; x2 = xb[512]; x3 = xb[768];  // bias folded
      }
      // concurrent polls: h2[U-1] (pure spin) and packed a2p[U]
      if (tid < 128) {
        const u32* src = &p.H2H[((size_t)(U - 1) * 32 + b) * 128 + tid];
        u32 v = AT_LOAD(src);
        int gd = 0;
        while (v == SENT && ++gd < (GUARD << 2)) v = AT_LOAD(src);
        f16x2 hp = __builtin_bit_cast(f16x2, v);
        hS[tid] = hp;
        tmp2[2 * tid] = (float)hp[0];
        tmp2[2 * tid + 1] = (float)hp[1];
      } else if (tid < 256) {
        int rr = tid - 128;
        int gp = rr >> 5, wp = rr & 31;
        const u32* src = &p.A2P[((size_t)U * 32 + b) * 512 + (gp << 7) + (q << 5) + wp];
        u32 v = AT_LOAD(src);
        int gd = 0;
        while (v == SENT && ++gd < GUARD) {
          __builtin_amdgcn_s_sleep(1);
          v = AT_LOAD(src);
        }
        f16x2 pr = __builtin_bit_cast(f16x2, v);
        a2pS[gp * 64 + 2 * wp] = (float)pr[0];
        a2pS[gp * 64 + 2 * wp + 1] = (float)pr[1];
      }
      __syncthreads();  // S1
      float a2p0 = 0, a2p1 = 0, a2p2 = 0, a2p3 = 0;
      if (tid < 64) {
        a2p0 = a2pS[tid]; a2p1 = a2pS[64 + tid];
        a2p2 = a2pS[128 + tid]; a2p3 = a2pS[192 + tid];
      }
      if (U <= 81) {
        if (U >= 2 && tid < 256) encL[U - 2][tid] = tmp2[tid];
      } else {
        // attention: q-vec = tmp2 (h2n[s-1]); parallel softmax; ctx -> hS
        float a = 0.f;
        if (tid < TE) {
          const float* e = &encL[tid][0];
#pragma unroll 8
          for (int k2 = 0; k2 < 256; ++k2) a += e[k2] * tmp2[k2];
        }
        float av = (tid < TE) ? a : -INFINITY;
#pragma unroll
        for (int d = 32; d; d >>= 1) av = fmaxf(av, __shfl_xor(av, d));
        if (tid == 0) red[0] = av;
        if (tid == 64) red[1] = av;
        __syncthreads();
        float m = fmaxf(red[0], red[1]);
        float e2 = (tid < TE) ? expf(a - m) : 0.f;
        float sv = e2;
#pragma unroll
        for (int d = 32; d; d >>= 1) sv += __shfl_xor(sv, d);
        if (tid == 0) red[2] = sv;
        if (tid == 64) red[3] = sv;
        __syncthreads();
        float inv = 1.0f / (red[2] + red[3]);
        if (tid < TE) sc[tid] = e2 * inv;
        __syncthreads();
        if (tid < 256) {
          float acc = 0.f;
          for (int t2 = 0; t2 < TE; ++t2) acc += sc[t2] * encL[t2][tid];
          tmp2[tid] = acc;
        }
        __syncthreads();
        if (tid < 128)
          hS[tid] = f16x2{(_Float16)tmp2[2 * tid], (_Float16)tmp2[2 * tid + 1]};
      }
      __syncthreads();
      float a2 = 0.f;
      {
        const uint4* hv = ((const uint4*)hS) + half * 16;
#pragma unroll
        for (int k = 0; k < 16; ++k) {
          uint4 uu = hv[k];
          a2 = fdot2h(__builtin_bit_cast(f16x2, uu.x), wC[k * 4 + 0], a2);
          a2 = fdot2h(__builtin_bit_cast(f16x2, uu.y), wC[k * 4 + 1], a2);
          a2 = fdot2h(__builtin_bit_cast(f16x2, uu.z), wC[k * 4 + 2], a2);
          a2 = fdot2h(__builtin_bit_cast(f16x2, uu.w), wC[k * 4 + 3], a2);
        }
      }
      a2 += __shfl_xor(a2, 1);
      if (half == 0) gb[r2] = a2;
      __syncthreads();
      if (tid < 64) {
        float gi = gb[tid] + a2p0 + x0;
        float gf = gb[64 + tid] + a2p1 + x1;
        float gG = gb[128 + tid] + a2p2 + x2;
        float go = gb[192 + tid] + a2p3 + x3;
        c2 = sigm(gf) * c2 + sigm(gi) * tanhf(gG);
        float h = sigm(go) * tanhf(c2);
        hnew[tid] = h;
        if (U >= 81)
          p.H2NB[((size_t)(U - 81) * 32 + b) * 256 + jf] = f2bf(h);
      }
      if (tid < 32) {  // same wave as hnew writers
        u32 pk = packh2(hnew[2 * tid], hnew[2 * tid + 1]);
        AT_STORE(&p.H2H[((size_t)U * 32 + b) * 128 + (q << 5) + tid], pk);
      }
    }
  }
}

// ===========================================================================
// Fused logits + CE partials + final reduce (250 co-resident blocks).
// ===========================================================================
__global__ __launch_bounds__(256, 1) void logits_final_kernel(
    const u16* __restrict__ H2NB, const float* __restrict__ w_out,
    const float* __restrict__ b_out, const int* __restrict__ targets,
    u32* __restrict__ pmaxA, u32* __restrict__ psumA, u32* __restrict__ tgtv,
    float* __restrict__ loss, int* __restrict__ ctrs, float* __restrict__ out) {
  __shared__ __align__(16) u16 bS[32768];
  __shared__ __align__(16) u16 aS[32 * 264];
  __shared__ int tS[32];
  __shared__ float sm[256];
  int tid = threadIdx.x, bid = blockIdx.x;
#pragma unroll
  for (int it = 0; it < 16; ++it) {
    int id = it * 256 + tid;
    int nt = id >> 9, rr = (id >> 5) & 15, kg = id & 31;
    int n = bid * 128 + nt * 16 + rr;
    const float* src = &w_out[(size_t)n * 256 + kg * 8];
    float4 v0 = *(const float4*)src;
    float4 v1 = *(const float4*)(src + 4);
    u16* dst = &bS[(size_t)((nt * 32 + kg) * 16 + rr) * 8];
    *(ushort4*)dst = make_ushort4(f2bf(v0.x), f2bf(v0.y), f2bf(v0.z), f2bf(v0.w));
    *(ushort4*)(dst + 4) = make_ushort4(f2bf(v1.x), f2bf(v1.y), f2bf(v1.z), f2bf(v1.w));
  }
  int wid = tid >> 6, lane = tid & 63, lcol = lane & 15, lk = lane >> 4;
  float bo[2];
#pragma unroll
  for (int n = 0; n < 2; ++n) bo[n] = b_out[(bid * 8 + wid * 2 + n) * 16 + lcol];

  for (int rg = 0; rg < 29; ++rg) {
    __syncthreads();
    for (int i = tid; i < 1024; i += 256) {
      int r = i >> 5, c8 = i & 31;
      *(uint4*)&aS[r * 264 + c8 * 8] =
          *(const uint4*)&H2NB[(size_t)rg * 8192 + r * 256 + c8 * 8];
    }
    if (tid < 32) tS[tid] = targets[rg * 32 + tid];
    __syncthreads();
    f32x4 acc[2][2];
#pragma unroll
    for (int m = 0; m < 2; ++m)
#pragma unroll
      for (int n = 0; n < 2; ++n) acc[m][n] = (f32x4){0.f, 0.f, 0.f, 0.f};
#pragma unroll
    for (int ks = 0; ks < 8; ++ks) {
      bf16x8 a0 = *(const bf16x8*)&aS[lcol * 264 + ks * 32 + lk * 8];
      bf16x8 a1 = *(const bf16x8*)&aS[(16 + lcol) * 264 + ks * 32 + lk * 8];
      bf16x8 b0 = *(const bf16x8*)&bS[(wid * 2) * 4096 + ((ks * 4 + lk) * 16 + lcol) * 8];
      bf16x8 b1 = *(const bf16x8*)&bS[(wid * 2 + 1) * 4096 + ((ks * 4 + lk) * 16 + lcol) * 8];
      acc[0][0] = __builtin_amdgcn_mfma_f32_16x16x32_bf16(a0, b0, acc[0][0], 0, 0, 0);
      acc[0][1] = __builtin_amdgcn_mfma_f32_16x16x32_bf16(a0, b1, acc[0][1], 0, 0, 0);
      acc[1][0] = __builtin_amdgcn_mfma_f32_16x16x32_bf16(a1, b0, acc[1][0], 0, 0, 0);
      acc[1][1] = __builtin_amdgcn_mfma_f32_16x16x32_bf16(a1, b1, acc[1][1], 0, 0, 0);
    }
    int nbase = (bid * 8 + wid * 2) * 16 + lcol;
#pragma unroll
    for (int m = 0; m < 2; ++m) {
      float pm[4], psv[4];
#pragma unroll
      for (int qq = 0; qq < 4; ++qq) {
        float v0 = acc[m][0][qq] + bo[0];
        float v1 = acc[m][1][qq] + bo[1];
        int r = m * 16 + lk * 4 + qq;
        int tg = tS[r];
        if (tg == nbase) AT_STORE(&tgtv[rg * 32 + r], __float_as_uint(v0));
        if (tg == nbase + 16) AT_STORE(&tgtv[rg * 32 + r], __float_as_uint(v1));
        float mx = fmaxf(v0, v1);
#pragma unroll
        for (int d = 1; d < 16; d <<= 1) mx = fmaxf(mx, __shfl_xor(mx, d));
        float e = expf(v0 - mx) + expf(v1 - mx);
#pragma unroll
        for (int d = 1; d < 16; d <<= 1) e += __shfl_xor(e, d);
        pm[qq] = mx;
        psv[qq] = e;
      }
      if (lcol == 0) {
        int chunk = bid * 4 + wid;
#pragma unroll
        for (int qq = 0; qq < 4; ++qq) {
          int r2 = rg * 32 + m * 16 + lk * 4 + qq;
          AT_STORE(&pmaxA[(size_t)r2 * 1000 + chunk], __float_as_uint(pm[qq]));
          AT_STORE(&psumA[(size_t)r2 * 1000 + chunk], __float_as_uint(psv[qq]));
        }
      }
    }
  }
  asm volatile("s_waitcnt vmcnt(0)" ::: "memory");
  __syncthreads();
  if (tid == 0) {
    __hip_atomic_fetch_add(&ctrs[0], 1, __ATOMIC_RELEASE, __HIP_MEMORY_SCOPE_AGENT);
    int gd = 0;
    while (__hip_atomic_load(&ctrs[0], __ATOMIC_ACQUIRE, __HIP_MEMORY_SCOPE_AGENT) < 250 &&
           ++gd < GUARD)
      __builtin_amdgcn_s_sleep(2);
  }
  __syncthreads();
#pragma unroll
  for (int k = 0; k < 4; ++k) {
    int row = bid * 4 + k;
    if (row < 928) {
      const u32* pm = pmaxA + (size_t)row * 1000;
      const u32* psv = psumA + (size_t)row * 1000;
      float m = -INFINITY;
      for (int c = tid; c < 1000; c += 256) m = fmaxf(m, __uint_as_float(AT_LOAD(&pm[c])));
      sm[tid] = m;
      __syncthreads();
      for (int off = 128; off; off >>= 1) {
        if (tid < off) sm[tid] = fmaxf(sm[tid], sm[tid + off]);
        __syncthreads();
      }
      float M = sm[0];
      __syncthreads();
      float s = 0.f;
      for (int c = tid; c < 1000; c += 256)
        s += __uint_as_float(AT_LOAD(&psv[c])) * expf(__uint_as_float(AT_LOAD(&pm[c])) - M);
      sm[tid] = s;
      __syncthreads();
      for (int off = 128; off; off >>= 1) {
        if (tid < off) sm[tid] += sm[tid + off];
        __syncthreads();
      }
      if (tid == 0) {
        float tv = __uint_as_float(AT_LOAD(&tgtv[row]));
        atomicAdd(loss, (M + logf(sm[0]) - tv) * (1.0f / 1024.0f));
      }
      __syncthreads();
    }
  }
  asm volatile("s_waitcnt vmcnt(0)" ::: "memory");
  if (tid == 0) {
    int old = __hip_atomic_fetch_add(&ctrs[32], 1, __ATOMIC_ACQ_REL, __HIP_MEMORY_SCOPE_AGENT);
    if (old == 249) out[0] = __uint_as_float(AT_LOAD((u32*)loss));
  }
}

// ---------------------------------------------------------------------------
extern "C" void kernel_launch(void* const* d_in, const int* in_sizes, int n_in,
                              void* d_out, int out_size, void* d_ws, size_t ws_size,
                              hipStream_t stream) {
  (void)in_sizes; (void)n_in; (void)out_size; (void)ws_size;
  const float* feat    = (const float*)d_in[0];
  const float* caption = (const float*)d_in[1];
  const float* onehot  = (const float*)d_in[2];
  const float* w_ih1   = (const float*)d_in[4];
  const float* w_hh1   = (const float*)d_in[5];
  const float* b_ih1   = (const float*)d_in[6];
  const float* b_hh1   = (const float*)d_in[7];
  const float* w_ih2   = (const float*)d_in[8];
  const float* w_hh2   = (const float*)d_in[9];
  const float* b_ih2   = (const float*)d_in[10];
  const float* b_hh2   = (const float*)d_in[11];
  const float* w_out   = (const float*)d_in[12];
  const float* b_out   = (const float*)d_in[13];

  char* p = (char*)d_ws;
  auto alloc = [&](size_t bytes) {
    char* r = p;
    p += (bytes + 255) & ~(size_t)255;
    return r;
  };
  float* X1      = (float*)alloc(2560ull * 1024 * 4);    // 10.5 MB
  float* XW2     = (float*)alloc(29ull * 32 * 1024 * 4); // 3.8 MB
  float* bias1   = (float*)alloc(1024 * 4);
  float* bias2   = (float*)alloc(1024 * 4);
  u32*   H1H     = (u32*)alloc(110ull * 32 * 128 * 4);   // 1.8 MB
  u32*   H2H     = (u32*)alloc(110ull * 32 * 128 * 4);   // 1.8 MB
  u32*   A2P     = (u32*)alloc(110ull * 32 * 512 * 4);   // 7.2 MB
  u16*   H2NB    = (u16*)alloc(29ull * 8192 * 2);
  u32*   pmaxA   = (u32*)alloc(928ull * 1000 * 4);
  u32*   psumA   = (u32*)alloc(928ull * 1000 * 4);
  u32*   tgtv    = (u32*)alloc(928 * 4);
  float* lossacc = (float*)alloc(256);
  int*   ctrs    = (int*)alloc(1024);
  int*   targets = (int*)alloc(29 * 32 * 4);

  gemm_x1_kernel<<<160, 256, 0, stream>>>(feat, w_ih1, b_ih1, b_hh1, X1);

  prep_kernel<<<2273, 256, 0, stream>>>(
      w_ih2, caption, onehot,
      b_ih1, b_hh1, b_ih2, b_hh2,
      XW2, bias1, bias2, H1H, H2H, A2P, lossacc, ctrs, targets);

  RP rp;
  rp.X1 = X1; rp.XW2 = XW2; rp.bias1 = bias1; rp.bias2 = bias2;
  rp.w_hh1 = w_hh1; rp.w_ih2 = w_ih2; rp.w_hh2 = w_hh2;
  rp.H1H = H1H; rp.H2H = H2H; rp.A2P = A2P; rp.H2NB = H2NB;
  void* args[] = {&rp};
  hipLaunchCooperativeKernel((const void*)recurrent_kernel, dim3(256), dim3(512),
                             args, 0, stream);

  logits_final_kernel<<<250, 256, 0, stream>>>(H2NB, w_out, b_out, targets,
                                               pmaxA, psumA, tgtv, lossacc, ctrs,
                                               (float*)d_out);
}

// Round 18
// 734.234 us; speedup vs baseline: 1.6489x; 1.0193x over previous
//
#include <hip/hip_runtime.h>
#include <hip/hip_bf16.h>
#include <math.h>

// Problem dims
#define BB 32
#define TE 80
#define FEAT 4096
#define HH 256
#define W2V 256
#define TD 30
#define VV 32000
#define G4 1024   // 4*H

typedef unsigned short u16;
typedef unsigned int u32;
using f32x4 = __attribute__((ext_vector_type(4))) float;
using bf16x8 = __attribute__((ext_vector_type(8))) short;
using f16x2 = __attribute__((ext_vector_type(2))) _Float16;

#define SENT 0xFFFFFFFFu
#define GUARD (1 << 22)

__device__ __forceinline__ float sigm(float x) { return 1.0f / (1.0f + expf(-x)); }
__device__ __forceinline__ u16 f2bf(float f) {
  u32 u = __float_as_uint(f);
  u32 r = (u + 0x7FFFu + ((u >> 16) & 1u)) >> 16;
  return (u16)r;
}
__device__ __forceinline__ u32 packh2(float lo, float hi) {
  f16x2 v = {(_Float16)lo, (_Float16)hi};
  return __builtin_bit_cast(u32, v);
}

#define AT_LOAD(p)     __hip_atomic_load((p), __ATOMIC_RELAXED, __HIP_MEMORY_SCOPE_AGENT)
#define AT_STORE(p, v) __hip_atomic_store((p), (v), __ATOMIC_RELAXED, __HIP_MEMORY_SCOPE_AGENT)

__device__ __forceinline__ float fdot2h(f16x2 a, f16x2 b, float c) {
#if __has_builtin(__builtin_amdgcn_fdot2)
  return __builtin_amdgcn_fdot2(a, b, c, false);
#else
  return c + (float)a[0] * (float)b[0] + (float)a[1] * (float)b[1];
#endif
}

// ===========================================================================
// prep: argmax | feat->bf16 | w_ih1->bf16 | XW2 MFMA (inline cvt, +bias) |
// H sentinels | A2P sentinels (packed) | misc.
// blocks: [0,928) | [928,3488) | [3488,4512) | [4512,4976) | [4976,5416) |
// [5416,5856) | 5856  => 5857 blocks.  All segments are pure streams.
// ===========================================================================
__global__ __launch_bounds__(256) void prep_kernel(
    const float* __restrict__ feat, const float* __restrict__ w_ih1,
    const float* __restrict__ w_ih2, const float* __restrict__ caption,
    const float* __restrict__ onehot,
    const float* __restrict__ b_ih1, const float* __restrict__ b_hh1,
    const float* __restrict__ b_ih2, const float* __restrict__ b_hh2,
    u16* __restrict__ featb, u16* __restrict__ w_ih1b,
    float* __restrict__ XW2,
    float* __restrict__ bias1, float* __restrict__ bias2,
    u32* __restrict__ H1H, u32* __restrict__ H2H, u32* __restrict__ A2P,
    float* __restrict__ loss, int* __restrict__ ctrs,
    int* __restrict__ targets) {
  __shared__ __align__(16) char psm[50688];
  int blk = blockIdx.x, tid = threadIdx.x;
  if (blk < 928) {
    int k = blk;  // (s-1)*32 + b
    int s = (k >> 5) + 1, b = k & 31;
    const float* row = &onehot[((size_t)b * TD + s) * VV];
    float bv = -INFINITY;
    int bi = 0x7fffffff;
    for (int v = tid; v < VV; v += 256) {
      float x = row[v];
      if (x > bv || (x == bv && v < bi)) { bv = x; bi = v; }
    }
    float* sv = (float*)psm;
    int* si = (int*)(psm + 1024);
    sv[tid] = bv; si[tid] = bi;
    __syncthreads();
    for (int off = 128; off; off >>= 1) {
      if (tid < off) {
        float ov = sv[tid + off]; int oi = si[tid + off];
        if (ov > sv[tid] || (ov == sv[tid] && oi < si[tid])) { sv[tid] = ov; si[tid] = oi; }
      }
      __syncthreads();
    }
    if (tid == 0) targets[k] = si[0];
  } else if (blk < 3488) {
    int i0 = (blk - 928) * 1024 + tid;  // float4 idx < 2,621,440
#pragma unroll
    for (int ii = 0; ii < 4; ++ii) {
      int i = i0 + ii * 256;
      float4 v = *(const float4*)&feat[(size_t)i * 4];
      *(ushort4*)&featb[(size_t)i * 4] =
          make_ushort4(f2bf(v.x), f2bf(v.y), f2bf(v.z), f2bf(v.w));
    }
  } else if (blk < 4512) {
    int i0 = (blk - 3488) * 1024 + tid;  // float4 idx < 1,048,576
#pragma unroll
    for (int ii = 0; ii < 4; ++ii) {
      int i = i0 + ii * 256;
      float4 v = *(const float4*)&w_ih1[(size_t)i * 4];
      *(ushort4*)&w_ih1b[(size_t)i * 4] =
          make_ushort4(f2bf(v.x), f2bf(v.y), f2bf(v.z), f2bf(v.w));
    }
  } else if (blk < 4976) {
    // XW2[(t*32+b)][n] = bf16(caption[b][t][:]) . bf16(w_ih2[n][0:256]) + bias2[n]
    int k = blk - 4512, nb = k & 15, t = k >> 4;
    u16* As = (u16*)psm;                 // [32][264]
    u16* Bs = (u16*)(psm + 16896);       // [64][264]
    int nBase = nb * 64;
#pragma unroll
    for (int it = 0; it < 4; ++it) {
      int i = it * 256 + tid;
      int r = i >> 5, c8 = i & 31;
      const float* src = &caption[((size_t)r * TD + t) * 256 + c8 * 8];
      float4 v0 = *(const float4*)src;
      float4 v1 = *(const float4*)(src + 4);
      u16* dst = &As[r * 264 + c8 * 8];
      *(ushort4*)dst = make_ushort4(f2bf(v0.x), f2bf(v0.y), f2bf(v0.z), f2bf(v0.w));
      *(ushort4*)(dst + 4) = make_ushort4(f2bf(v1.x), f2bf(v1.y), f2bf(v1.z), f2bf(v1.w));
    }
#pragma unroll
    for (int it = 0; it < 8; ++it) {
      int i = it * 256 + tid;
      int r = i >> 5, c8 = i & 31;
      const float* src = &w_ih2[(size_t)(nBase + r) * 512 + c8 * 8];
      float4 v0 = *(const float4*)src;
      float4 v1 = *(const float4*)(src + 4);
      u16* dst = &Bs[r * 264 + c8 * 8];
      *(ushort4*)dst = make_ushort4(f2bf(v0.x), f2bf(v0.y), f2bf(v0.z), f2bf(v0.w));
      *(ushort4*)(dst + 4) = make_ushort4(f2bf(v1.x), f2bf(v1.y), f2bf(v1.z), f2bf(v1.w));
    }
    __syncthreads();
    int lane = tid & 63, w = tid >> 6;
    int lrow = lane & 15, lk = (lane >> 4) * 8;
    f32x4 acc[2];
    acc[0] = (f32x4){0.f, 0.f, 0.f, 0.f};
    acc[1] = (f32x4){0.f, 0.f, 0.f, 0.f};
#pragma unroll
    for (int ks = 0; ks < 8; ++ks) {
      bf16x8 bfr = *(const bf16x8*)&Bs[(w * 16 + lrow) * 264 + ks * 32 + lk];
#pragma unroll
      for (int m = 0; m < 2; ++m) {
        bf16x8 af = *(const bf16x8*)&As[(m * 16 + lrow) * 264 + ks * 32 + lk];
        acc[m] = __builtin_amdgcn_mfma_f32_16x16x32_bf16(af, bfr, acc[m], 0, 0, 0);
      }
    }
    int col = nBase + w * 16 + (lane & 15);
    float bv = b_ih2[col] + b_hh2[col];
    int orow = (lane >> 4) * 4;
#pragma unroll
    for (int m = 0; m < 2; ++m)
#pragma unroll
      for (int qq = 0; qq < 4; ++qq) {
        int bb = m * 16 + orow + qq;
        XW2[((size_t)t * 32 + bb) * G4 + col] = acc[m][qq] + bv;
      }
  } else if (blk < 5416) {
    int i = (blk - 4976) * 256 + tid;  // uint4 idx < 112640
    uint4 z = {0u, 0u, 0u, 0u};
    uint4 s = {SENT, SENT, SENT, SENT};
    uint4 v = (i < 1024) ? z : s;      // slot T=0 = packed f16 zeros
    ((uint4*)H1H)[i] = v;
    ((uint4*)H2H)[i] = v;
  } else if (blk < 5856) {
    int i = (blk - 5416) * 256 + tid;  // uint4 idx < 112640 x4 = 450560
    uint4 s = {SENT, SENT, SENT, SENT};
    ((uint4*)A2P)[i] = s;
    ((uint4*)A2P)[i + 112640] = s;
    ((uint4*)A2P)[i + 225280] = s;
    ((uint4*)A2P)[i + 337920] = s;
  } else {
    for (int i = tid; i < 1024; i += 256) {
      bias1[i] = b_ih1[i] + b_hh1[i];
      bias2[i] = b_ih2[i] + b_hh2[i];
    }
    if (tid < 256) ctrs[tid] = 0;
    if (tid == 0) *loss = 0.0f;
  }
}

// ===========================================================================
// gemm_x1: X1[r][n] = featb[r][:] . w_ih1b[n][:] + bias1[n]  (bf16 inputs)
// ===========================================================================
#define GBM 128
#define GBN 128
#define GBK 64
#define LDSTR 72

__global__ __launch_bounds__(256) void gemm_x1_kernel(
    const u16* __restrict__ Ab, const u16* __restrict__ Bw,
    const float* __restrict__ bias, float* __restrict__ C) {
  __shared__ __align__(16) u16 As[GBM * LDSTR];
  __shared__ __align__(16) u16 Bs[GBN * LDSTR];
  int tid = threadIdx.x;
  int rBase = (blockIdx.x >> 3) * GBM;
  int nBase = (blockIdx.x & 7) * GBN;
  int lane = tid & 63, w = tid >> 6;
  int wrow = (w >> 1) * 64, wcol = (w & 1) * 64;
  int lrow = lane & 15, lk = (lane >> 4) * 8;

  f32x4 acc[4][4];
#pragma unroll
  for (int m = 0; m < 4; ++m)
#pragma unroll
    for (int n = 0; n < 4; ++n) acc[m][n] = (f32x4){0.f, 0.f, 0.f, 0.f};

  for (int k0 = 0; k0 < FEAT; k0 += GBK) {
#pragma unroll
    for (int i = 0; i < 4; ++i) {
      int f = i * 256 + tid;  // uint4 id 0..1023
      int r = f >> 3, c8 = f & 7;
      *(uint4*)&As[r * LDSTR + c8 * 8] =
          *(const uint4*)&Ab[(size_t)(rBase + r) * FEAT + k0 + c8 * 8];
    }
#pragma unroll
    for (int i = 0; i < 4; ++i) {
      int f = i * 256 + tid;
      int r = f >> 3, c8 = f & 7;
      *(uint4*)&Bs[r * LDSTR + c8 * 8] =
          *(const uint4*)&Bw[(size_t)(nBase + r) * FEAT + k0 + c8 * 8];
    }
    __syncthreads();
#pragma unroll
    for (int s2 = 0; s2 < 2; ++s2) {
      bf16x8 af[4], bfr[4];
#pragma unroll
      for (int m = 0; m < 4; ++m)
        af[m] = *(const bf16x8*)&As[(wrow + m * 16 + lrow) * LDSTR + s2 * 32 + lk];
#pragma unroll
      for (int n = 0; n < 4; ++n)
        bfr[n] = *(const bf16x8*)&Bs[(wcol + n * 16 + lrow) * LDSTR + s2 * 32 + lk];
#pragma unroll
      for (int m = 0; m < 4; ++m)
#pragma unroll
        for (int n = 0; n < 4; ++n)
          acc[m][n] = __builtin_amdgcn_mfma_f32_16x16x32_bf16(
              af[m], bfr[n], acc[m][n], 0, 0, 0);
    }
    __syncthreads();
  }
  int orow = (lane >> 4) * 4;
  int ocol = lane & 15;
#pragma unroll
  for (int m = 0; m < 4; ++m)
#pragma unroll
    for (int n = 0; n < 4; ++n) {
      int cidx = nBase + wcol + n * 16 + ocol;
      float bv = bias[cidx];
#pragma unroll
      for (int q = 0; q < 4; ++q) {
        int r = rBase + wrow + m * 16 + orow + q;
        C[(size_t)r * G4 + cidx] = acc[m][n][q] + bv;
      }
    }
}

// ===========================================================================
// Persistent recurrent kernel (r17 verbatim; packed A2P, a2p offload).
// ===========================================================================
struct RP {
  const float *X1, *XW2, *bias1, *bias2;
  const float *w_hh1, *w_ih2, *w_hh2;
  u32* H1H;     // [110][32][128] packed f16x2 of h1[T]
  u32* H2H;     // [110][32][128] packed f16x2 of h2[U]
  u32* A2P;     // [110][32][512] packed f16x2 pairs of a2 rows
  u16* H2NB;    // [29][32][256] bf16 decoder h2n
};

__global__ __launch_bounds__(512, 1) void recurrent_kernel(RP p) {
  __shared__ float encL[TE][257];
  __shared__ __align__(16) f16x2 hS[128];
  __shared__ float tmp2[256];
  __shared__ float gb[256];
  __shared__ float a2pS[256];
  __shared__ float hnew[64];
  __shared__ float sc[80];
  __shared__ float red[4];
  int bid = blockIdx.x, tid = threadIdx.x;
  bool isL1 = bid < 128;
  int lb = isL1 ? bid : bid - 128;
  int b = lb >> 2, q = lb & 3;
  int r2 = tid >> 1, half = tid & 1;
  int g = r2 >> 6, jj = r2 & 63;
  int grow = (g << 8) + (q << 6) + jj;
  int jf = (q << 6) + tid;  // valid for tid<64

  if (isL1) {
    f16x2 wA[64], wB[64];
    {
      const float4* sA = (const float4*)(p.w_hh1 + (size_t)grow * 256 + half * 128);
      const float4* sB = (const float4*)(p.w_ih2 + (size_t)grow * 512 + 256 + half * 128);
#pragma unroll
      for (int k = 0; k < 32; ++k) {
        float4 v = sA[k];
        wA[k * 2 + 0] = f16x2{(_Float16)v.x, (_Float16)v.y};
        wA[k * 2 + 1] = f16x2{(_Float16)v.z, (_Float16)v.w};
        float4 u = sB[k];
        wB[k * 2 + 0] = f16x2{(_Float16)u.x, (_Float16)u.y};
        wB[k * 2 + 1] = f16x2{(_Float16)u.z, (_Float16)u.w};
      }
    }
    float c1 = 0.f;
    float b1v0 = 0, b1v1 = 0, b1v2 = 0, b1v3 = 0;
    if (tid < 64) {
      b1v0 = p.bias1[jf]; b1v1 = p.bias1[256 + jf];
      b1v2 = p.bias1[512 + jf]; b1v3 = p.bias1[768 + jf];
    }
    for (int T = 0; T <= 109; ++T) {
      float x0 = b1v0, x1 = b1v1, x2 = b1v2, x3 = b1v3;
      if (tid < 64 && T < TE) {
        const float* xb = &p.X1[((size_t)b * TE + T) * G4 + jf];
        x0 = xb[0]; x1 = xb[256]; x2 = xb[512]; x3 = xb[768];
      }
      if (tid < 128) {
        const u32* src = &p.H1H[((size_t)T * 32 + b) * 128 + tid];
        u32 v = AT_LOAD(src);
        int gd = 0;
        while (v == SENT && ++gd < GUARD) {
          __builtin_amdgcn_s_sleep(1);
          v = AT_LOAD(src);
        }
        hS[tid] = __builtin_bit_cast(f16x2, v);
      }
      __syncthreads();  // S1
      float a1 = 0.f, a2 = 0.f;
      {
        const uint4* hv = ((const uint4*)hS) + half * 16;
#pragma unroll
        for (int k = 0; k < 16; ++k) {
          uint4 uu = hv[k];
          f16x2 e0 = __builtin_bit_cast(f16x2, uu.x), e1 = __builtin_bit_cast(f16x2, uu.y);
          f16x2 e2 = __builtin_bit_cast(f16x2, uu.z), e3 = __builtin_bit_cast(f16x2, uu.w);
          a1 = fdot2h(e0, wA[k * 4 + 0], a1);
          a2 = fdot2h(e0, wB[k * 4 + 0], a2);
          a1 = fdot2h(e1, wA[k * 4 + 1], a1);
          a2 = fdot2h(e1, wB[k * 4 + 1], a2);
          a1 = fdot2h(e2, wA[k * 4 + 2], a1);
          a2 = fdot2h(e2, wB[k * 4 + 2], a2);
          a1 = fdot2h(e3, wA[k * 4 + 3], a1);
          a2 = fdot2h(e3, wB[k * 4 + 3], a2);
        }
      }
      a1 += __shfl_xor(a1, 1);
      a2 += __shfl_xor(a2, 1);
      float a2o = __shfl_xor(a2, 2);  // partner row's a2
      if (half == 0) gb[r2] = a1;
      if ((tid & 3) == 0 && T >= 1) {
        int pr = tid >> 2;  // pair 0..127
        int gp = pr >> 5, wp = pr & 31;
        AT_STORE(&p.A2P[((size_t)T * 32 + b) * 512 + (gp << 7) + (q << 5) + wp],
                 packh2(a2, a2o));
      }
      __syncthreads();  // S2
      if (T <= 108) {
        if (tid < 64) {
          float gi = gb[tid] + x0;
          float gf = gb[64 + tid] + x1;
          float gG = gb[128 + tid] + x2;
          float go = gb[192 + tid] + x3;
          c1 = sigm(gf) * c1 + sigm(gi) * tanhf(gG);
          hnew[tid] = sigm(go) * tanhf(c1);
        }
        if (tid < 32) {  // same wave as hnew writers
          u32 pk = packh2(hnew[2 * tid], hnew[2 * tid + 1]);
          AT_STORE(&p.H1H[((size_t)(T + 1) * 32 + b) * 128 + (q << 5) + tid], pk);
        }
      }
    }
  } else {
    f16x2 wC[64];
    {
      const float4* sC = (const float4*)(p.w_hh2 + (size_t)grow * 256 + half * 128);
#pragma unroll
      for (int k = 0; k < 32; ++k) {
        float4 u = sC[k];
        wC[k * 2 + 0] = f16x2{(_Float16)u.x, (_Float16)u.y};
        wC[k * 2 + 1] = f16x2{(_Float16)u.z, (_Float16)u.w};
      }
    }
    float c2 = 0.f;
    float b2v0 = 0, b2v1 = 0, b2v2 = 0, b2v3 = 0;
    if (tid < 64) {
      b2v0 = p.bias2[jf]; b2v1 = p.bias2[256 + jf];
      b2v2 = p.bias2[512 + jf]; b2v3 = p.bias2[768 + jf];
    }
    for (int U = 1; U <= 109; ++U) {
      float x0 = b2v0, x1 = b2v1, x2 = b2v2, x3 = b2v3;
      if (tid < 64 && U >= 81) {
        const float* xb = &p.XW2[((size_t)(U - 81) * 32 + b) * G4 + jf];
        x0 = xb[0]; x1 = xb[256]; x2 = xb[512]; x3 = xb[768];  // bias folded
      }
      // concurrent polls: h2[U-1] (pure spin) and packed a2p[U]
      if (tid < 128) {
        const u32* src = &p.H2H[((size_t)(U - 1) * 32 + b) * 128 + tid];
        u32 v = AT_LOAD(src);
        int gd = 0;
        while (v == SENT && ++gd < (GUARD << 2)) v = AT_LOAD(src);
        f16x2 hp = __builtin_bit_cast(f16x2, v);
        hS[tid] = hp;
        tmp2[2 * tid] = (float)hp[0];
        tmp2[2 * tid + 1] = (float)hp[1];
      } else if (tid < 256) {
        int rr = tid - 128;
        int gp = rr >> 5, wp = rr & 31;
        const u32* src = &p.A2P[((size_t)U * 32 + b) * 512 + (gp << 7) + (q << 5) + wp];
        u32 v = AT_LOAD(src);
        int gd = 0;
        while (v == SENT && ++gd < GUARD) {
          __builtin_amdgcn_s_sleep(1);
          v = AT_LOAD(src);
        }
        f16x2 pr = __builtin_bit_cast(f16x2, v);
        a2pS[gp * 64 + 2 * wp] = (float)pr[0];
        a2pS[gp * 64 + 2 * wp + 1] = (float)pr[1];
      }
      __syncthreads();  // S1
      float a2p0 = 0, a2p1 = 0, a2p2 = 0, a2p3 = 0;
      if (tid < 64) {
        a2p0 = a2pS[tid]; a2p1 = a2pS[64 + tid];
        a2p2 = a2pS[128 + tid]; a2p3 = a2pS[192 + tid];
      }
      if (U <= 81) {
        if (U >= 2 && tid < 256) encL[U - 2][tid] = tmp2[tid];
      } else {
        // attention: q-vec = tmp2 (h2n[s-1]); parallel softmax; ctx -> hS
        float a = 0.f;
        if (tid < TE) {
          const float* e = &encL[tid][0];
#pragma unroll 8
          for (int k2 = 0; k2 < 256; ++k2) a += e[k2] * tmp2[k2];
        }
        float av = (tid < TE) ? a : -INFINITY;
#pragma unroll
        for (int d = 32; d; d >>= 1) av = fmaxf(av, __shfl_xor(av, d));
        if (tid == 0) red[0] = av;
        if (tid == 64) red[1] = av;
        __syncthreads();
        float m = fmaxf(red[0], red[1]);
        float e2 = (tid < TE) ? expf(a - m) : 0.f;
        float sv = e2;
#pragma unroll
        for (int d = 32; d; d >>= 1) sv += __shfl_xor(sv, d);
        if (tid == 0) red[2] = sv;
        if (tid == 64) red[3] = sv;
        __syncthreads();
        float inv = 1.0f / (red[2] + red[3]);
        if (tid < TE) sc[tid] = e2 * inv;
        __syncthreads();
        if (tid < 256) {
          float acc = 0.f;
          for (int t2 = 0; t2 < TE; ++t2) acc += sc[t2] * encL[t2][tid];
          tmp2[tid] = acc;
        }
        __syncthreads();
        if (tid < 128)
          hS[tid] = f16x2{(_Float16)tmp2[2 * tid], (_Float16)tmp2[2 * tid + 1]};
      }
      __syncthreads();
      float a2 = 0.f;
      {
        const uint4* hv = ((const uint4*)hS) + half * 16;
#pragma unroll
        for (int k = 0; k < 16; ++k) {
          uint4 uu = hv[k];
          a2 = fdot2h(__builtin_bit_cast(f16x2, uu.x), wC[k * 4 + 0], a2);
          a2 = fdot2h(__builtin_bit_cast(f16x2, uu.y), wC[k * 4 + 1], a2);
          a2 = fdot2h(__builtin_bit_cast(f16x2, uu.z), wC[k * 4 + 2], a2);
          a2 = fdot2h(__builtin_bit_cast(f16x2, uu.w), wC[k * 4 + 3], a2);
        }
      }
      a2 += __shfl_xor(a2, 1);
      if (half == 0) gb[r2] = a2;
      __syncthreads();
      if (tid < 64) {
        float gi = gb[tid] + a2p0 + x0;
        float gf = gb[64 + tid] + a2p1 + x1;
        float gG = gb[128 + tid] + a2p2 + x2;
        float go = gb[192 + tid] + a2p3 + x3;
        c2 = sigm(gf) * c2 + sigm(gi) * tanhf(gG);
        float h = sigm(go) * tanhf(c2);
        hnew[tid] = h;
        if (U >= 81)
          p.H2NB[((size_t)(U - 81) * 32 + b) * 256 + jf] = f2bf(h);
      }
      if (tid < 32) {  // same wave as hnew writers
        u32 pk = packh2(hnew[2 * tid], hnew[2 * tid + 1]);
        AT_STORE(&p.H2H[((size_t)U * 32 + b) * 128 + (q << 5) + tid], pk);
      }
    }
  }
}

// ===========================================================================
// Fused logits + CE partials + final reduce (250 co-resident blocks).
// ===========================================================================
__global__ __launch_bounds__(256, 1) void logits_final_kernel(
    const u16* __restrict__ H2NB, const float* __restrict__ w_out,
    const float* __restrict__ b_out, const int* __restrict__ targets,
    u32* __restrict__ pmaxA, u32* __restrict__ psumA, u32* __restrict__ tgtv,
    float* __restrict__ loss, int* __restrict__ ctrs, float* __restrict__ out) {
  __shared__ __align__(16) u16 bS[32768];
  __shared__ __align__(16) u16 aS[32 * 264];
  __shared__ int tS[32];
  __shared__ float sm[256];
  int tid = threadIdx.x, bid = blockIdx.x;
#pragma unroll
  for (int it = 0; it < 16; ++it) {
    int id = it * 256 + tid;
    int nt = id >> 9, rr = (id >> 5) & 15, kg = id & 31;
    int n = bid * 128 + nt * 16 + rr;
    const float* src = &w_out[(size_t)n * 256 + kg * 8];
    float4 v0 = *(const float4*)src;
    float4 v1 = *(const float4*)(src + 4);
    u16* dst = &bS[(size_t)((nt * 32 + kg) * 16 + rr) * 8];
    *(ushort4*)dst = make_ushort4(f2bf(v0.x), f2bf(v0.y), f2bf(v0.z), f2bf(v0.w));
    *(ushort4*)(dst + 4) = make_ushort4(f2bf(v1.x), f2bf(v1.y), f2bf(v1.z), f2bf(v1.w));
  }
  int wid = tid >> 6, lane = tid & 63, lcol = lane & 15, lk = lane >> 4;
  float bo[2];
#pragma unroll
  for (int n = 0; n < 2; ++n) bo[n] = b_out[(bid * 8 + wid * 2 + n) * 16 + lcol];

  for (int rg = 0; rg < 29; ++rg) {
    __syncthreads();
    for (int i = tid; i < 1024; i += 256) {
      int r = i >> 5, c8 = i & 31;
      *(uint4*)&aS[r * 264 + c8 * 8] =
          *(const uint4*)&H2NB[(size_t)rg * 8192 + r * 256 + c8 * 8];
    }
    if (tid < 32) tS[tid] = targets[rg * 32 + tid];
    __syncthreads();
    f32x4 acc[2][2];
#pragma unroll
    for (int m = 0; m < 2; ++m)
#pragma unroll
      for (int n = 0; n < 2; ++n) acc[m][n] = (f32x4){0.f, 0.f, 0.f, 0.f};
#pragma unroll
    for (int ks = 0; ks < 8; ++ks) {
      bf16x8 a0 = *(const bf16x8*)&aS[lcol * 264 + ks * 32 + lk * 8];
      bf16x8 a1 = *(const bf16x8*)&aS[(16 + lcol) * 264 + ks * 32 + lk * 8];
      bf16x8 b0 = *(const bf16x8*)&bS[(wid * 2) * 4096 + ((ks * 4 + lk) * 16 + lcol) * 8];
      bf16x8 b1 = *(const bf16x8*)&bS[(wid * 2 + 1) * 4096 + ((ks * 4 + lk) * 16 + lcol) * 8];
      acc[0][0] = __builtin_amdgcn_mfma_f32_16x16x32_bf16(a0, b0, acc[0][0], 0, 0, 0);
      acc[0][1] = __builtin_amdgcn_mfma_f32_16x16x32_bf16(a0, b1, acc[0][1], 0, 0, 0);
      acc[1][0] = __builtin_amdgcn_mfma_f32_16x16x32_bf16(a1, b0, acc[1][0], 0, 0, 0);
      acc[1][1] = __builtin_amdgcn_mfma_f32_16x16x32_bf16(a1, b1, acc[1][1], 0, 0, 0);
    }
    int nbase = (bid * 8 + wid * 2) * 16 + lcol;
#pragma unroll
    for (int m = 0; m < 2; ++m) {
      float pm[4], psv[4];
#pragma unroll
      for (int qq = 0; qq < 4; ++qq) {
        float v0 = acc[m][0][qq] + bo[0];
        float v1 = acc[m][1][qq] + bo[1];
        int r = m * 16 + lk * 4 + qq;
        int tg = tS[r];
        if (tg == nbase) AT_STORE(&tgtv[rg * 32 + r], __float_as_uint(v0));
        if (tg == nbase + 16) AT_STORE(&tgtv[rg * 32 + r], __float_as_uint(v1));
        float mx = fmaxf(v0, v1);
#pragma unroll
        for (int d = 1; d < 16; d <<= 1) mx = fmaxf(mx, __shfl_xor(mx, d));
        float e = expf(v0 - mx) + expf(v1 - mx);
#pragma unroll
        for (int d = 1; d < 16; d <<= 1) e += __shfl_xor(e, d);
        pm[qq] = mx;
        psv[qq] = e;
      }
      if (lcol == 0) {
        int chunk = bid * 4 + wid;
#pragma unroll
        for (int qq = 0; qq < 4; ++qq) {
          int r2 = rg * 32 + m * 16 + lk * 4 + qq;
          AT_STORE(&pmaxA[(size_t)r2 * 1000 + chunk], __float_as_uint(pm[qq]));
          AT_STORE(&psumA[(size_t)r2 * 1000 + chunk], __float_as_uint(psv[qq]));
        }
      }
    }
  }
  asm volatile("s_waitcnt vmcnt(0)" ::: "memory");
  __syncthreads();
  if (tid == 0) {
    __hip_atomic_fetch_add(&ctrs[0], 1, __ATOMIC_RELEASE, __HIP_MEMORY_SCOPE_AGENT);
    int gd = 0;
    while (__hip_atomic_load(&ctrs[0], __ATOMIC_ACQUIRE, __HIP_MEMORY_SCOPE_AGENT) < 250 &&
           ++gd < GUARD)
      __builtin_amdgcn_s_sleep(2);
  }
  __syncthreads();
#pragma unroll
  for (int k = 0; k < 4; ++k) {
    int row = bid * 4 + k;
    if (row < 928) {
      const u32* pm = pmaxA + (size_t)row * 1000;
      const u32* psv = psumA + (size_t)row * 1000;
      float m = -INFINITY;
      for (int c = tid; c < 1000; c += 256) m = fmaxf(m, __uint_as_float(AT_LOAD(&pm[c])));
      sm[tid] = m;
      __syncthreads();
      for (int off = 128; off; off >>= 1) {
        if (tid < off) sm[tid] = fmaxf(sm[tid], sm[tid + off]);
        __syncthreads();
      }
      float M = sm[0];
      __syncthreads();
      float s = 0.f;
      for (int c = tid; c < 1000; c += 256)
        s += __uint_as_float(AT_LOAD(&psv[c])) * expf(__uint_as_float(AT_LOAD(&pm[c])) - M);
      sm[tid] = s;
      __syncthreads();
      for (int off = 128; off; off >>= 1) {
        if (tid < off) sm[tid] += sm[tid + off];
        __syncthreads();
      }
      if (tid == 0) {
        float tv = __uint_as_float(AT_LOAD(&tgtv[row]));
        atomicAdd(loss, (M + logf(sm[0]) - tv) * (1.0f / 1024.0f));
      }
      __syncthreads();
    }
  }
  asm volatile("s_waitcnt vmcnt(0)" ::: "memory");
  if (tid == 0) {
    int old = __hip_atomic_fetch_add(&ctrs[32], 1, __ATOMIC_ACQ_REL, __HIP_MEMORY_SCOPE_AGENT);
    if (old == 249) out[0] = __uint_as_float(AT_LOAD((u32*)loss));
  }
}

// ---------------------------------------------------------------------------
extern "C" void kernel_launch(void* const* d_in, const int* in_sizes, int n_in,
                              void* d_out, int out_size, void* d_ws, size_t ws_size,
                              hipStream_t stream) {
  (void)in_sizes; (void)n_in; (void)out_size; (void)ws_size;
  const float* feat    = (const float*)d_in[0];
  const float* caption = (const float*)d_in[1];
  const float* onehot  = (const float*)d_in[2];
  const float* w_ih1   = (const float*)d_in[4];
  const float* w_hh1   = (const float*)d_in[5];
  const float* b_ih1   = (const float*)d_in[6];
  const float* b_hh1   = (const float*)d_in[7];
  const float* w_ih2   = (const float*)d_in[8];
  const float* w_hh2   = (const float*)d_in[9];
  const float* b_ih2   = (const float*)d_in[10];
  const float* b_hh2   = (const float*)d_in[11];
  const float* w_out   = (const float*)d_in[12];
  const float* b_out   = (const float*)d_in[13];

  char* p = (char*)d_ws;
  auto alloc = [&](size_t bytes) {
    char* r = p;
    p += (bytes + 255) & ~(size_t)255;
    return r;
  };
  float* X1      = (float*)alloc(2560ull * 1024 * 4);    // 10.5 MB
  float* XW2     = (float*)alloc(29ull * 32 * 1024 * 4); // 3.8 MB
  float* bias1   = (float*)alloc(1024 * 4);
  float* bias2   = (float*)alloc(1024 * 4);
  u32*   H1H     = (u32*)alloc(110ull * 32 * 128 * 4);   // 1.8 MB
  u32*   H2H     = (u32*)alloc(110ull * 32 * 128 * 4);   // 1.8 MB
  u32*   A2P     = (u32*)alloc(110ull * 32 * 512 * 4);   // 7.2 MB
  u16*   H2NB    = (u16*)alloc(29ull * 8192 * 2);
  u32*   pmaxA   = (u32*)alloc(928ull * 1000 * 4);
  u32*   psumA   = (u32*)alloc(928ull * 1000 * 4);
  u32*   tgtv    = (u32*)alloc(928 * 4);
  float* lossacc = (float*)alloc(256);
  int*   ctrs    = (int*)alloc(1024);
  int*   targets = (int*)alloc(29 * 32 * 4);
  u16*   featb   = (u16*)alloc(2560ull * 4096 * 2);      // 21 MB
  u16*   w_ih1b  = (u16*)alloc(1024ull * 4096 * 2);      // 8.4 MB

  prep_kernel<<<5857, 256, 0, stream>>>(
      feat, w_ih1, w_ih2, caption, onehot,
      b_ih1, b_hh1, b_ih2, b_hh2,
      featb, w_ih1b, XW2, bias1, bias2, H1H, H2H, A2P, lossacc, ctrs, targets);

  gemm_x1_kernel<<<160, 256, 0, stream>>>(featb, w_ih1b, bias1, X1);

  RP rp;
  rp.X1 = X1; rp.XW2 = XW2; rp.bias1 = bias1; rp.bias2 = bias2;
  rp.w_hh1 = w_hh1; rp.w_ih2 = w_ih2; rp.w_hh2 = w_hh2;
  rp.H1H = H1H; rp.H2H = H2H; rp.A2P = A2P; rp.H2NB = H2NB;
  void* args[] = {&rp};
  hipLaunchCooperativeKernel((const void*)recurrent_kernel, dim3(256), dim3(512),
                             args, 0, stream);

  logits_final_kernel<<<250, 256, 0, stream>>>(H2NB, w_out, b_out, targets,
                                               pmaxA, psumA, tgtv, lossacc, ctrs,
                                               (float*)d_out);
}

// Round 19
// 734.201 us; speedup vs baseline: 1.6490x; 1.0000x over previous
//
#include <hip/hip_runtime.h>
#include <hip/hip_bf16.h>
#include <math.h>

// Problem dims
#define BB 32
#define TE 80
#define FEAT 4096
#define HH 256
#define W2V 256
#define TD 30
#define VV 32000
#define G4 1024   // 4*H

typedef unsigned short u16;
typedef unsigned int u32;
using f32x4 = __attribute__((ext_vector_type(4))) float;
using bf16x8 = __attribute__((ext_vector_type(8))) short;
using f16x2 = __attribute__((ext_vector_type(2))) _Float16;

#define SENT 0xFFFFFFFFu
#define GUARD (1 << 22)

__device__ __forceinline__ float sigm(float x) { return 1.0f / (1.0f + expf(-x)); }
__device__ __forceinline__ u16 f2bf(float f) {
  u32 u = __float_as_uint(f);
  u32 r = (u + 0x7FFFu + ((u >> 16) & 1u)) >> 16;
  return (u16)r;
}
__device__ __forceinline__ u32 packh2(float lo, float hi) {
  f16x2 v = {(_Float16)lo, (_Float16)hi};
  return __builtin_bit_cast(u32, v);
}

#define AT_LOAD(p)     __hip_atomic_load((p), __ATOMIC_RELAXED, __HIP_MEMORY_SCOPE_AGENT)
#define AT_STORE(p, v) __hip_atomic_store((p), (v), __ATOMIC_RELAXED, __HIP_MEMORY_SCOPE_AGENT)

__device__ __forceinline__ float fdot2h(f16x2 a, f16x2 b, float c) {
#if __has_builtin(__builtin_amdgcn_fdot2)
  return __builtin_amdgcn_fdot2(a, b, c, false);
#else
  return c + (float)a[0] * (float)b[0] + (float)a[1] * (float)b[1];
#endif
}

// ===========================================================================
// prep (r14-proven): argmax | w_ih1->bf16 | XW2 MFMA | H sentinels |
// A2P packed sentinels | bias+misc.   3297 blocks.
// ===========================================================================
__global__ __launch_bounds__(256) void prep_kernel(
    const float* __restrict__ w_ih1, const float* __restrict__ w_ih2,
    const float* __restrict__ caption, const float* __restrict__ onehot,
    const float* __restrict__ b_ih1, const float* __restrict__ b_hh1,
    const float* __restrict__ b_ih2, const float* __restrict__ b_hh2,
    u16* __restrict__ w_ih1b, float* __restrict__ XW2,
    float* __restrict__ bias1, float* __restrict__ bias2,
    u32* __restrict__ H1H, u32* __restrict__ H2H, u32* __restrict__ A2P,
    float* __restrict__ loss, int* __restrict__ ctrs,
    int* __restrict__ targets) {
  __shared__ __align__(16) char psm[50688];
  int blk = blockIdx.x, tid = threadIdx.x;
  if (blk < 928) {
    int k = blk;  // (s-1)*32 + b
    int s = (k >> 5) + 1, b = k & 31;
    const float* row = &onehot[((size_t)b * TD + s) * VV];
    float bv = -INFINITY;
    int bi = 0x7fffffff;
    for (int v = tid; v < VV; v += 256) {
      float x = row[v];
      if (x > bv || (x == bv && v < bi)) { bv = x; bi = v; }
    }
    float* sv = (float*)psm;
    int* si = (int*)(psm + 1024);
    sv[tid] = bv; si[tid] = bi;
    __syncthreads();
    for (int off = 128; off; off >>= 1) {
      if (tid < off) {
        float ov = sv[tid + off]; int oi = si[tid + off];
        if (ov > sv[tid] || (ov == sv[tid] && oi < si[tid])) { sv[tid] = ov; si[tid] = oi; }
      }
      __syncthreads();
    }
    if (tid == 0) targets[k] = si[0];
  } else if (blk < 1952) {
    int i0 = (blk - 928) * 1024 + tid;
#pragma unroll
    for (int ii = 0; ii < 4; ++ii) {
      int i = i0 + ii * 256;
      float4 v = *(const float4*)&w_ih1[(size_t)i * 4];
      *(ushort4*)&w_ih1b[(size_t)i * 4] =
          make_ushort4(f2bf(v.x), f2bf(v.y), f2bf(v.z), f2bf(v.w));
    }
  } else if (blk < 2416) {
    // XW2[(t*32+b)][n] = bf16(caption[b][t][:]) . bf16(w_ih2[n][0:256]) + bias2[n]
    int k = blk - 1952, nb = k & 15, t = k >> 4;
    u16* As = (u16*)psm;                 // [32][264]
    u16* Bs = (u16*)(psm + 16896);       // [64][264]
    int nBase = nb * 64;
#pragma unroll
    for (int it = 0; it < 4; ++it) {
      int i = it * 256 + tid;
      int r = i >> 5, c8 = i & 31;
      const float* src = &caption[((size_t)r * TD + t) * 256 + c8 * 8];
      float4 v0 = *(const float4*)src;
      float4 v1 = *(const float4*)(src + 4);
      u16* dst = &As[r * 264 + c8 * 8];
      *(ushort4*)dst = make_ushort4(f2bf(v0.x), f2bf(v0.y), f2bf(v0.z), f2bf(v0.w));
      *(ushort4*)(dst + 4) = make_ushort4(f2bf(v1.x), f2bf(v1.y), f2bf(v1.z), f2bf(v1.w));
    }
#pragma unroll
    for (int it = 0; it < 8; ++it) {
      int i = it * 256 + tid;
      int r = i >> 5, c8 = i & 31;
      const float* src = &w_ih2[(size_t)(nBase + r) * 512 + c8 * 8];
      float4 v0 = *(const float4*)src;
      float4 v1 = *(const float4*)(src + 4);
      u16* dst = &Bs[r * 264 + c8 * 8];
      *(ushort4*)dst = make_ushort4(f2bf(v0.x), f2bf(v0.y), f2bf(v0.z), f2bf(v0.w));
      *(ushort4*)(dst + 4) = make_ushort4(f2bf(v1.x), f2bf(v1.y), f2bf(v1.z), f2bf(v1.w));
    }
    __syncthreads();
    int lane = tid & 63, w = tid >> 6;
    int lrow = lane & 15, lk = (lane >> 4) * 8;
    f32x4 acc[2];
    acc[0] = (f32x4){0.f, 0.f, 0.f, 0.f};
    acc[1] = (f32x4){0.f, 0.f, 0.f, 0.f};
#pragma unroll
    for (int ks = 0; ks < 8; ++ks) {
      bf16x8 bfr = *(const bf16x8*)&Bs[(w * 16 + lrow) * 264 + ks * 32 + lk];
#pragma unroll
      for (int m = 0; m < 2; ++m) {
        bf16x8 af = *(const bf16x8*)&As[(m * 16 + lrow) * 264 + ks * 32 + lk];
        acc[m] = __builtin_amdgcn_mfma_f32_16x16x32_bf16(af, bfr, acc[m], 0, 0, 0);
      }
    }
    int col = nBase + w * 16 + (lane & 15);
    float bv = b_ih2[col] + b_hh2[col];
    int orow = (lane >> 4) * 4;
#pragma unroll
    for (int m = 0; m < 2; ++m)
#pragma unroll
      for (int qq = 0; qq < 4; ++qq) {
        int bb = m * 16 + orow + qq;
        XW2[((size_t)t * 32 + bb) * G4 + col] = acc[m][qq] + bv;
      }
  } else if (blk < 2856) {
    int i = (blk - 2416) * 256 + tid;  // uint4 idx < 112640
    uint4 z = {0u, 0u, 0u, 0u};
    uint4 s = {SENT, SENT, SENT, SENT};
    uint4 v = (i < 1024) ? z : s;      // slot T=0 = packed f16 zeros
    ((uint4*)H1H)[i] = v;
    ((uint4*)H2H)[i] = v;
  } else if (blk < 3296) {
    int i = (blk - 2856) * 256 + tid;  // uint4 idx, A2P = 450560 u32 = 112640 uint4
    uint4 s = {SENT, SENT, SENT, SENT};
    if (i < 112640) ((uint4*)A2P)[i] = s;
  } else {
    for (int i = tid; i < 1024; i += 256) {
      bias1[i] = b_ih1[i] + b_hh1[i];
      bias2[i] = b_ih2[i] + b_hh2[i];
    }
    if (tid < 256) ctrs[tid] = 0;
    if (tid == 0) *loss = 0.0f;
  }
}

// ===========================================================================
// gemm_x1 (r14-proven): X1 = feat(f32, inline cvt) . w_ih1b(bf16)^T + bias1
// ===========================================================================
#define GBM 128
#define GBN 128
#define GBK 64
#define LDSTR 72

__global__ __launch_bounds__(256) void gemm_x1_kernel(
    const float* __restrict__ A, const u16* __restrict__ Bw,
    const float* __restrict__ bias, float* __restrict__ C) {
  __shared__ __align__(16) u16 As[GBM * LDSTR];
  __shared__ __align__(16) u16 Bs[GBN * LDSTR];
  int tid = threadIdx.x;
  int rBase = (blockIdx.x >> 3) * GBM;
  int nBase = (blockIdx.x & 7) * GBN;
  int lane = tid & 63, w = tid >> 6;
  int wrow = (w >> 1) * 64, wcol = (w & 1) * 64;
  int lrow = lane & 15, lk = (lane >> 4) * 8;

  f32x4 acc[4][4];
#pragma unroll
  for (int m = 0; m < 4; ++m)
#pragma unroll
    for (int n = 0; n < 4; ++n) acc[m][n] = (f32x4){0.f, 0.f, 0.f, 0.f};

  for (int k0 = 0; k0 < FEAT; k0 += GBK) {
#pragma unroll
    for (int i = 0; i < 8; ++i) {
      int f = i * 256 + tid;
      int r = f >> 4, c = (f & 15) << 2;
      float4 v = *(const float4*)&A[(size_t)(rBase + r) * FEAT + k0 + c];
      *(ushort4*)&As[r * LDSTR + c] =
          make_ushort4(f2bf(v.x), f2bf(v.y), f2bf(v.z), f2bf(v.w));
    }
#pragma unroll
    for (int i = 0; i < 4; ++i) {
      int f = i * 256 + tid;
      int r = f >> 3, c8 = f & 7;
      *(uint4*)&Bs[r * LDSTR + c8 * 8] =
          *(const uint4*)&Bw[(size_t)(nBase + r) * FEAT + k0 + c8 * 8];
    }
    __syncthreads();
#pragma unroll
    for (int s2 = 0; s2 < 2; ++s2) {
      bf16x8 af[4], bfr[4];
#pragma unroll
      for (int m = 0; m < 4; ++m)
        af[m] = *(const bf16x8*)&As[(wrow + m * 16 + lrow) * LDSTR + s2 * 32 + lk];
#pragma unroll
      for (int n = 0; n < 4; ++n)
        bfr[n] = *(const bf16x8*)&Bs[(wcol + n * 16 + lrow) * LDSTR + s2 * 32 + lk];
#pragma unroll
      for (int m = 0; m < 4; ++m)
#pragma unroll
        for (int n = 0; n < 4; ++n)
          acc[m][n] = __builtin_amdgcn_mfma_f32_16x16x32_bf16(
              af[m], bfr[n], acc[m][n], 0, 0, 0);
    }
    __syncthreads();
  }
  int orow = (lane >> 4) * 4;
  int ocol = lane & 15;
#pragma unroll
  for (int m = 0; m < 4; ++m)
#pragma unroll
    for (int n = 0; n < 4; ++n) {
      int cidx = nBase + wcol + n * 16 + ocol;
      float bv = bias[cidx];
#pragma unroll
      for (int q = 0; q < 4; ++q) {
        int r = rBase + wrow + m * 16 + orow + q;
        C[(size_t)r * G4 + cidx] = acc[m][n][q] + bv;
      }
    }
}

// ===========================================================================
// Persistent recurrent kernel (r17 verbatim; packed A2P, a2p offload).
// ===========================================================================
struct RP {
  const float *X1, *XW2, *bias1, *bias2;
  const float *w_hh1, *w_ih2, *w_hh2;
  u32* H1H;     // [110][32][128] packed f16x2 of h1[T]
  u32* H2H;     // [110][32][128] packed f16x2 of h2[U]
  u32* A2P;     // [110][32][512] packed f16x2 pairs of a2 rows
  u16* H2NB;    // [29][32][256] bf16 decoder h2n
};

__global__ __launch_bounds__(512, 1) void recurrent_kernel(RP p) {
  __shared__ float encL[TE][257];
  __shared__ __align__(16) f16x2 hS[128];
  __shared__ float tmp2[256];
  __shared__ float gb[256];
  __shared__ float a2pS[256];
  __shared__ float hnew[64];
  __shared__ float sc[80];
  __shared__ float red[4];
  int bid = blockIdx.x, tid = threadIdx.x;
  bool isL1 = bid < 128;
  int lb = isL1 ? bid : bid - 128;
  int b = lb >> 2, q = lb & 3;
  int r2 = tid >> 1, half = tid & 1;
  int g = r2 >> 6, jj = r2 & 63;
  int grow = (g << 8) + (q << 6) + jj;
  int jf = (q << 6) + tid;  // valid for tid<64

  if (isL1) {
    f16x2 wA[64], wB[64];
    {
      const float4* sA = (const float4*)(p.w_hh1 + (size_t)grow * 256 + half * 128);
      const float4* sB = (const float4*)(p.w_ih2 + (size_t)grow * 512 + 256 + half * 128);
#pragma unroll
      for (int k = 0; k < 32; ++k) {
        float4 v = sA[k];
        wA[k * 2 + 0] = f16x2{(_Float16)v.x, (_Float16)v.y};
        wA[k * 2 + 1] = f16x2{(_Float16)v.z, (_Float16)v.w};
        float4 u = sB[k];
        wB[k * 2 + 0] = f16x2{(_Float16)u.x, (_Float16)u.y};
        wB[k * 2 + 1] = f16x2{(_Float16)u.z, (_Float16)u.w};
      }
    }
    float c1 = 0.f;
    float b1v0 = 0, b1v1 = 0, b1v2 = 0, b1v3 = 0;
    if (tid < 64) {
      b1v0 = p.bias1[jf]; b1v1 = p.bias1[256 + jf];
      b1v2 = p.bias1[512 + jf]; b1v3 = p.bias1[768 + jf];
    }
    for (int T = 0; T <= 109; ++T) {
      float x0 = b1v0, x1 = b1v1, x2 = b1v2, x3 = b1v3;
      if (tid < 64 && T < TE) {
        const float* xb = &p.X1[((size_t)b * TE + T) * G4 + jf];
        x0 = xb[0]; x1 = xb[256]; x2 = xb[512]; x3 = xb[768];
      }
      if (tid < 128) {
        const u32* src = &p.H1H[((size_t)T * 32 + b) * 128 + tid];
        u32 v = AT_LOAD(src);
        int gd = 0;
        while (v == SENT && ++gd < GUARD) {
          __builtin_amdgcn_s_sleep(1);
          v = AT_LOAD(src);
        }
        hS[tid] = __builtin_bit_cast(f16x2, v);
      }
      __syncthreads();  // S1
      float a1 = 0.f, a2 = 0.f;
      {
        const uint4* hv = ((const uint4*)hS) + half * 16;
#pragma unroll
        for (int k = 0; k < 16; ++k) {
          uint4 uu = hv[k];
          f16x2 e0 = __builtin_bit_cast(f16x2, uu.x), e1 = __builtin_bit_cast(f16x2, uu.y);
          f16x2 e2 = __builtin_bit_cast(f16x2, uu.z), e3 = __builtin_bit_cast(f16x2, uu.w);
          a1 = fdot2h(e0, wA[k * 4 + 0], a1);
          a2 = fdot2h(e0, wB[k * 4 + 0], a2);
          a1 = fdot2h(e1, wA[k * 4 + 1], a1);
          a2 = fdot2h(e1, wB[k * 4 + 1], a2);
          a1 = fdot2h(e2, wA[k * 4 + 2], a1);
          a2 = fdot2h(e2, wB[k * 4 + 2], a2);
          a1 = fdot2h(e3, wA[k * 4 + 3], a1);
          a2 = fdot2h(e3, wB[k * 4 + 3], a2);
        }
      }
      a1 += __shfl_xor(a1, 1);
      a2 += __shfl_xor(a2, 1);
      float a2o = __shfl_xor(a2, 2);  // partner row's a2
      if (half == 0) gb[r2] = a1;
      if ((tid & 3) == 0 && T >= 1) {
        int pr = tid >> 2;  // pair 0..127
        int gp = pr >> 5, wp = pr & 31;
        AT_STORE(&p.A2P[((size_t)T * 32 + b) * 512 + (gp << 7) + (q << 5) + wp],
                 packh2(a2, a2o));
      }
      __syncthreads();  // S2
      if (T <= 108) {
        if (tid < 64) {
          float gi = gb[tid] + x0;
          float gf = gb[64 + tid] + x1;
          float gG = gb[128 + tid] + x2;
          float go = gb[192 + tid] + x3;
          c1 = sigm(gf) * c1 + sigm(gi) * tanhf(gG);
          hnew[tid] = sigm(go) * tanhf(c1);
        }
        if (tid < 32) {  // same wave as hnew writers
          u32 pk = packh2(hnew[2 * tid], hnew[2 * tid + 1]);
          AT_STORE(&p.H1H[((size_t)(T + 1) * 32 + b) * 128 + (q << 5) + tid], pk);
        }
      }
    }
  } else {
    f16x2 wC[64];
    {
      const float4* sC = (const float4*)(p.w_hh2 + (size_t)grow * 256 + half * 128);
#pragma unroll
      for (int k = 0; k < 32; ++k) {
        float4 u = sC[k];
        wC[k * 2 + 0] = f16x2{(_Float16)u.x, (_Float16)u.y};
        wC[k * 2 + 1] = f16x2{(_Float16)u.z, (_Float16)u.w};
      }
    }
    float c2 = 0.f;
    float b2v0 = 0, b2v1 = 0, b2v2 = 0, b2v3 = 0;
    if (tid < 64) {
      b2v0 = p.bias2[jf]; b2v1 = p.bias2[256 + jf];
      b2v2 = p.bias2[512 + jf]; b2v3 = p.bias2[768 + jf];
    }
    for (int U = 1; U <= 109; ++U) {
      float x0 = b2v0, x1 = b2v1, x2 = b2v2, x3 = b2v3;
      if (tid < 64 && U >= 81) {
        const float* xb = &p.XW2[((size_t)(U - 81) * 32 + b) * G4 + jf];
        x0 = xb[0]; x1 = xb[256]; x2 = xb[512]; x3 = xb[768];  // bias folded
      }
      // concurrent polls: h2[U-1] (pure spin) and packed a2p[U]
      if (tid < 128) {
        const u32* src = &p.H2H[((size_t)(U - 1) * 32 + b) * 128 + tid];
        u32 v = AT_LOAD(src);
        int gd = 0;
        while (v == SENT && ++gd < (GUARD << 2)) v = AT_LOAD(src);
        f16x2 hp = __builtin_bit_cast(f16x2, v);
        hS[tid] = hp;
        tmp2[2 * tid] = (float)hp[0];
        tmp2[2 * tid + 1] = (float)hp[1];
      } else if (tid < 256) {
        int rr = tid - 128;
        int gp = rr >> 5, wp = rr & 31;
        const u32* src = &p.A2P[((size_t)U * 32 + b) * 512 + (gp << 7) + (q << 5) + wp];
        u32 v = AT_LOAD(src);
        int gd = 0;
        while (v == SENT && ++gd < GUARD) {
          __builtin_amdgcn_s_sleep(1);
          v = AT_LOAD(src);
        }
        f16x2 pr = __builtin_bit_cast(f16x2, v);
        a2pS[gp * 64 + 2 * wp] = (float)pr[0];
        a2pS[gp * 64 + 2 * wp + 1] = (float)pr[1];
      }
      __syncthreads();  // S1
      float a2p0 = 0, a2p1 = 0, a2p2 = 0, a2p3 = 0;
      if (tid < 64) {
        a2p0 = a2pS[tid]; a2p1 = a2pS[64 + tid];
        a2p2 = a2pS[128 + tid]; a2p3 = a2pS[192 + tid];
      }
      if (U <= 81) {
        if (U >= 2 && tid < 256) encL[U - 2][tid] = tmp2[tid];
      } else {
        // attention: q-vec = tmp2 (h2n[s-1]); parallel softmax; ctx -> hS
        float a = 0.f;
        if (tid < TE) {
          const float* e = &encL[tid][0];
#pragma unroll 8
          for (int k2 = 0; k2 < 256; ++k2) a += e[k2] * tmp2[k2];
        }
        float av = (tid < TE) ? a : -INFINITY;
#pragma unroll
        for (int d = 32; d; d >>= 1) av = fmaxf(av, __shfl_xor(av, d));
        if (tid == 0) red[0] = av;
        if (tid == 64) red[1] = av;
        __syncthreads();
        float m = fmaxf(red[0], red[1]);
        float e2 = (tid < TE) ? expf(a - m) : 0.f;
        float sv = e2;
#pragma unroll
        for (int d = 32; d; d >>= 1) sv += __shfl_xor(sv, d);
        if (tid == 0) red[2] = sv;
        if (tid == 64) red[3] = sv;
        __syncthreads();
        float inv = 1.0f / (red[2] + red[3]);
        if (tid < TE) sc[tid] = e2 * inv;
        __syncthreads();
        if (tid < 256) {
          float acc = 0.f;
          for (int t2 = 0; t2 < TE; ++t2) acc += sc[t2] * encL[t2][tid];
          tmp2[tid] = acc;
        }
        __syncthreads();
        if (tid < 128)
          hS[tid] = f16x2{(_Float16)tmp2[2 * tid], (_Float16)tmp2[2 * tid + 1]};
      }
      __syncthreads();
      float a2 = 0.f;
      {
        const uint4* hv = ((const uint4*)hS) + half * 16;
#pragma unroll
        for (int k = 0; k < 16; ++k) {
          uint4 uu = hv[k];
          a2 = fdot2h(__builtin_bit_cast(f16x2, uu.x), wC[k * 4 + 0], a2);
          a2 = fdot2h(__builtin_bit_cast(f16x2, uu.y), wC[k * 4 + 1], a2);
          a2 = fdot2h(__builtin_bit_cast(f16x2, uu.z), wC[k * 4 + 2], a2);
          a2 = fdot2h(__builtin_bit_cast(f16x2, uu.w), wC[k * 4 + 3], a2);
        }
      }
      a2 += __shfl_xor(a2, 1);
      if (half == 0) gb[r2] = a2;
      __syncthreads();
      if (tid < 64) {
        float gi = gb[tid] + a2p0 + x0;
        float gf = gb[64 + tid] + a2p1 + x1;
        float gG = gb[128 + tid] + a2p2 + x2;
        float go = gb[192 + tid] + a2p3 + x3;
        c2 = sigm(gf) * c2 + sigm(gi) * tanhf(gG);
        float h = sigm(go) * tanhf(c2);
        hnew[tid] = h;
        if (U >= 81)
          p.H2NB[((size_t)(U - 81) * 32 + b) * 256 + jf] = f2bf(h);
      }
      if (tid < 32) {  // same wave as hnew writers
        u32 pk = packh2(hnew[2 * tid], hnew[2 * tid + 1]);
        AT_STORE(&p.H2H[((size_t)U * 32 + b) * 128 + (q << 5) + tid], pk);
      }
    }
  }
}

// ===========================================================================
// logits_ce (250 blocks): batched logits MFMA + fused CE partials.
// Plain stores (kernel boundary provides visibility to ce_final).
// ===========================================================================
__global__ __launch_bounds__(256, 1) void logits_ce_kernel(
    const u16* __restrict__ H2NB, const float* __restrict__ w_out,
    const float* __restrict__ b_out, const int* __restrict__ targets,
    float* __restrict__ pmaxA, float* __restrict__ psumA,
    float* __restrict__ tgtv) {
  __shared__ __align__(16) u16 bS[32768];
  __shared__ __align__(16) u16 aS[32 * 264];
  __shared__ int tS[32];
  int tid = threadIdx.x, bid = blockIdx.x;
#pragma unroll
  for (int it = 0; it < 16; ++it) {
    int id = it * 256 + tid;
    int nt = id >> 9, rr = (id >> 5) & 15, kg = id & 31;
    int n = bid * 128 + nt * 16 + rr;
    const float* src = &w_out[(size_t)n * 256 + kg * 8];
    float4 v0 = *(const float4*)src;
    float4 v1 = *(const float4*)(src + 4);
    u16* dst = &bS[(size_t)((nt * 32 + kg) * 16 + rr) * 8];
    *(ushort4*)dst = make_ushort4(f2bf(v0.x), f2bf(v0.y), f2bf(v0.z), f2bf(v0.w));
    *(ushort4*)(dst + 4) = make_ushort4(f2bf(v1.x), f2bf(v1.y), f2bf(v1.z), f2bf(v1.w));
  }
  int wid = tid >> 6, lane = tid & 63, lcol = lane & 15, lk = lane >> 4;
  float bo[2];
#pragma unroll
  for (int n = 0; n < 2; ++n) bo[n] = b_out[(bid * 8 + wid * 2 + n) * 16 + lcol];

  for (int rg = 0; rg < 29; ++rg) {
    __syncthreads();
    for (int i = tid; i < 1024; i += 256) {
      int r = i >> 5, c8 = i & 31;
      *(uint4*)&aS[r * 264 + c8 * 8] =
          *(const uint4*)&H2NB[(size_t)rg * 8192 + r * 256 + c8 * 8];
    }
    if (tid < 32) tS[tid] = targets[rg * 32 + tid];
    __syncthreads();
    f32x4 acc[2][2];
#pragma unroll
    for (int m = 0; m < 2; ++m)
#pragma unroll
      for (int n = 0; n < 2; ++n) acc[m][n] = (f32x4){0.f, 0.f, 0.f, 0.f};
#pragma unroll
    for (int ks = 0; ks < 8; ++ks) {
      bf16x8 a0 = *(const bf16x8*)&aS[lcol * 264 + ks * 32 + lk * 8];
      bf16x8 a1 = *(const bf16x8*)&aS[(16 + lcol) * 264 + ks * 32 + lk * 8];
      bf16x8 b0 = *(const bf16x8*)&bS[(wid * 2) * 4096 + ((ks * 4 + lk) * 16 + lcol) * 8];
      bf16x8 b1 = *(const bf16x8*)&bS[(wid * 2 + 1) * 4096 + ((ks * 4 + lk) * 16 + lcol) * 8];
      acc[0][0] = __builtin_amdgcn_mfma_f32_16x16x32_bf16(a0, b0, acc[0][0], 0, 0, 0);
      acc[0][1] = __builtin_amdgcn_mfma_f32_16x16x32_bf16(a0, b1, acc[0][1], 0, 0, 0);
      acc[1][0] = __builtin_amdgcn_mfma_f32_16x16x32_bf16(a1, b0, acc[1][0], 0, 0, 0);
      acc[1][1] = __builtin_amdgcn_mfma_f32_16x16x32_bf16(a1, b1, acc[1][1], 0, 0, 0);
    }
    int nbase = (bid * 8 + wid * 2) * 16 + lcol;
#pragma unroll
    for (int m = 0; m < 2; ++m) {
      float pm[4], psv[4];
#pragma unroll
      for (int qq = 0; qq < 4; ++qq) {
        float v0 = acc[m][0][qq] + bo[0];
        float v1 = acc[m][1][qq] + bo[1];
        int r = m * 16 + lk * 4 + qq;
        int tg = tS[r];
        if (tg == nbase) tgtv[rg * 32 + r] = v0;
        if (tg == nbase + 16) tgtv[rg * 32 + r] = v1;
        float mx = fmaxf(v0, v1);
#pragma unroll
        for (int d = 1; d < 16; d <<= 1) mx = fmaxf(mx, __shfl_xor(mx, d));
        float e = expf(v0 - mx) + expf(v1 - mx);
#pragma unroll
        for (int d = 1; d < 16; d <<= 1) e += __shfl_xor(e, d);
        pm[qq] = mx;
        psv[qq] = e;
      }
      if (lcol == 0) {
        int chunk = bid * 4 + wid;
#pragma unroll
        for (int qq = 0; qq < 4; ++qq) {
          int r2 = rg * 32 + m * 16 + lk * 4 + qq;
          pmaxA[(size_t)r2 * 1000 + chunk] = pm[qq];
          psumA[(size_t)r2 * 1000 + chunk] = psv[qq];
        }
      }
    }
  }
}

// ===========================================================================
// ce_final (928 blocks, one row each); last finisher writes d_out.
// ===========================================================================
__global__ __launch_bounds__(256) void ce_final_kernel(
    const float* __restrict__ pmaxA, const float* __restrict__ psumA,
    const float* __restrict__ tgtv, float* __restrict__ loss,
    int* __restrict__ ctrs, float* __restrict__ out) {
  int row = blockIdx.x;
  int tid = threadIdx.x;
  const float* pm = pmaxA + (size_t)row * 1000;
  const float* psv = psumA + (size_t)row * 1000;
  __shared__ float sm[256];
  float m = -INFINITY;
  for (int c = tid; c < 1000; c += 256) m = fmaxf(m, pm[c]);
  sm[tid] = m;
  __syncthreads();
  for (int off = 128; off; off >>= 1) {
    if (tid < off) sm[tid] = fmaxf(sm[tid], sm[tid + off]);
    __syncthreads();
  }
  float M = sm[0];
  __syncthreads();
  float s = 0.f;
  for (int c = tid; c < 1000; c += 256) s += psv[c] * expf(pm[c] - M);
  sm[tid] = s;
  __syncthreads();
  for (int off = 128; off; off >>= 1) {
    if (tid < off) sm[tid] += sm[tid + off];
    __syncthreads();
  }
  if (tid == 0) {
    atomicAdd(loss, (M + logf(sm[0]) - tgtv[row]) * (1.0f / 1024.0f));
    asm volatile("s_waitcnt vmcnt(0)" ::: "memory");
    int old = __hip_atomic_fetch_add(&ctrs[32], 1, __ATOMIC_ACQ_REL,
                                     __HIP_MEMORY_SCOPE_AGENT);
    if (old == 927) out[0] = __uint_as_float(AT_LOAD((u32*)loss));
  }
}

// ---------------------------------------------------------------------------
extern "C" void kernel_launch(void* const* d_in, const int* in_sizes, int n_in,
                              void* d_out, int out_size, void* d_ws, size_t ws_size,
                              hipStream_t stream) {
  (void)in_sizes; (void)n_in; (void)out_size; (void)ws_size;
  const float* feat    = (const float*)d_in[0];
  const float* caption = (const float*)d_in[1];
  const float* onehot  = (const float*)d_in[2];
  const float* w_ih1   = (const float*)d_in[4];
  const float* w_hh1   = (const float*)d_in[5];
  const float* b_ih1   = (const float*)d_in[6];
  const float* b_hh1   = (const float*)d_in[7];
  const float* w_ih2   = (const float*)d_in[8];
  const float* w_hh2   = (const float*)d_in[9];
  const float* b_ih2   = (const float*)d_in[10];
  const float* b_hh2   = (const float*)d_in[11];
  const float* w_out   = (const float*)d_in[12];
  const float* b_out   = (const float*)d_in[13];

  char* p = (char*)d_ws;
  auto alloc = [&](size_t bytes) {
    char* r = p;
    p += (bytes + 255) & ~(size_t)255;
    return r;
  };
  float* X1      = (float*)alloc(2560ull * 1024 * 4);    // 10.5 MB
  float* XW2     = (float*)alloc(29ull * 32 * 1024 * 4); // 3.8 MB
  float* bias1   = (float*)alloc(1024 * 4);
  float* bias2   = (float*)alloc(1024 * 4);
  u32*   H1H     = (u32*)alloc(110ull * 32 * 128 * 4);   // 1.8 MB
  u32*   H2H     = (u32*)alloc(110ull * 32 * 128 * 4);   // 1.8 MB
  u32*   A2P     = (u32*)alloc(110ull * 32 * 512 * 4);   // 7.2 MB
  u16*   H2NB    = (u16*)alloc(29ull * 8192 * 2);
  float* pmaxA   = (float*)alloc(928ull * 1000 * 4);
  float* psumA   = (float*)alloc(928ull * 1000 * 4);
  float* tgtv    = (float*)alloc(928 * 4);
  float* lossacc = (float*)alloc(256);
  int*   ctrs    = (int*)alloc(1024);
  int*   targets = (int*)alloc(29 * 32 * 4);
  u16*   w_ih1b  = (u16*)alloc(1024ull * 4096 * 2);      // 8.4 MB

  prep_kernel<<<3297, 256, 0, stream>>>(
      w_ih1, w_ih2, caption, onehot,
      b_ih1, b_hh1, b_ih2, b_hh2,
      w_ih1b, XW2, bias1, bias2, H1H, H2H, A2P, lossacc, ctrs, targets);

  gemm_x1_kernel<<<160, 256, 0, stream>>>(feat, w_ih1b, bias1, X1);

  RP rp;
  rp.X1 = X1; rp.XW2 = XW2; rp.bias1 = bias1; rp.bias2 = bias2;
  rp.w_hh1 = w_hh1; rp.w_ih2 = w_ih2; rp.w_hh2 = w_hh2;
  rp.H1H = H1H; rp.H2H = H2H; rp.A2P = A2P; rp.H2NB = H2NB;
  void* args[] = {&rp};
  hipLaunchCooperativeKernel((const void*)recurrent_kernel, dim3(256), dim3(512),
                             args, 0, stream);

  logits_ce_kernel<<<250, 256, 0, stream>>>(H2NB, w_out, b_out, targets,
                                            pmaxA, psumA, tgtv);
  ce_final_kernel<<<928, 256, 0, stream>>>(pmaxA, psumA, tgtv, lossacc, ctrs,
                                           (float*)d_out);
}